// Round 6
// baseline (941.641 us; speedup 1.0000x reference)
//
#include <hip/hip_runtime.h>
#include <stdint.h>

#define F_FRAMES 1296
#define JC 24
#define CH 256
#define NH 8
#define EMAX 120
#define M1 31104
#define N1 1536
#define K1 256
#define M2 22144
#define MREAL 22032
#define K2 1280
#define N2 256

typedef __attribute__((ext_vector_type(8))) short s8v;
typedef __attribute__((ext_vector_type(4))) short s4v;
typedef __attribute__((ext_vector_type(4))) float f4v;

#define GLOBAL_AS __attribute__((address_space(1)))
#define LDS_AS __attribute__((address_space(3)))

__device__ __forceinline__ float b2f(uint16_t u){
  union { float f; uint32_t u; } v; v.u = ((uint32_t)u) << 16; return v.f;
}
__device__ __forceinline__ uint16_t f2b(float f){
  union { float f; uint32_t u; } v; v.f = f;
  uint32_t u = v.u;
  uint32_t r = (u + 0x7fffu + ((u >> 16) & 1u)) >> 16;
  return (uint16_t)r;
}

// ---------------- dtype detection -------------------------------------------
__global__ __launch_bounds__(256) void detect_kernel(const uint16_t* __restrict__ x,
                                                     int* __restrict__ flag){
  __shared__ int cnt;
  if (threadIdx.x == 0) cnt = 0;
  __syncthreads();
  int good = 0;
  for (int i = threadIdx.x; i < 512; i += 256){
    uint16_t v = x[i];
    int e = (v >> 7) & 0xFF;
    good += (e >= 115 && e <= 131) ? 1 : 0;
  }
  atomicAdd(&cnt, good);
  __syncthreads();
  if (threadIdx.x == 0) *flag = (cnt >= 400) ? 1 : 0;
}

// ---------------- convert all float inputs into a bf16 arena ----------------
struct Ptrs { const void* p[21]; };

__constant__ int c_off[22] = {
  0, 5640192, 6033408, 6033472, 6033728, 6033984, 6427200, 6427264, 6427520,
  6427776, 6820992, 6821056, 6821312, 6821568, 7214784, 7214848, 7215104,
  7215360, 7543040, 7543296, 7543552, 7543808};

__global__ __launch_bounds__(256) void convert_kernel(Ptrs ptrs,
        const int* __restrict__ flag, uint16_t* __restrict__ arena){
  long base = ((long)blockIdx.x * 256 + threadIdx.x) * 8;
  if (base >= 7543808L) return;
  int seg = 0;
  while (c_off[seg + 1] <= base) seg++;
  long loc = base - c_off[seg];
  if (*flag){
    *(s8v*)(arena + base) = *(const s8v*)((const uint16_t*)ptrs.p[seg] + loc);
  } else {
    const float* s = (const float*)ptrs.p[seg] + loc;
    f4v a = *(const f4v*)s;
    f4v b = *(const f4v*)(s + 4);
    s8v o;
    #pragma unroll
    for (int u = 0; u < 4; u++){ o[u] = (short)f2b(a[u]); o[4+u] = (short)f2b(b[u]); }
    *(s8v*)(arena + base) = o;
  }
}

// ---------------- prep ---------------------------------------------------------
__global__ __launch_bounds__(256) void prep_kernel(const uint16_t* __restrict__ x,
                     uint16_t* __restrict__ xc0, uint16_t* __restrict__ y){
  long i = (long)blockIdx.x * 256 + threadIdx.x;
  const long n1 = (long)F_FRAMES * JC * CH;
  const long n2 = (long)MREAL * CH;
  const long n3 = (long)(M2 - MREAL) * K2;
  if (i < n1){
    long f = i / (JC*CH); long r = i % (JC*CH);
    int j = (int)(r >> 8); int c = (int)(r & 255);
    uint16_t v = 0;
    if (j < 17) v = x[(f*17 + j)*CH + c];
    xc0[i] = v;
  } else if (i < n1 + n2){
    long i2 = i - n1;
    long row = i2 >> 8; int c = (int)(i2 & 255);
    y[row*K2 + c] = x[i2];
  } else if (i < n1 + n2 + n3){
    long i3 = i - n1 - n2;
    long row = MREAL + i3 / K2; int c = (int)(i3 % K2);
    y[row*K2 + c] = 0;
  }
}

// ---------------- build per-src edge lists (once per call) -------------------
__global__ __launch_bounds__(64) void build_elist(const int* __restrict__ eskel,
        const int* __restrict__ ecay, int* __restrict__ out){
  int t = threadIdx.x;
  int g = t >> 5, j = t & 31;
  if (j < 24){
    const int* ed = g ? ecay : eskel;
    int E = g ? 120 : 49;
    int c = 0;
    for (int e = 0; e < E; e++)
      if (ed[e] == j){ out[48 + (g*24 + j)*8 + c] = e; c++; }
    out[g*24 + j] = c;
  }
}

// ---------------- GEMM (used for final projection only) ----------------------
template<int OUT_F32>
__global__ __launch_bounds__(256) void gemm_bt(const uint16_t* __restrict__ A,
        const uint16_t* __restrict__ B, void* __restrict__ Cv,
        int M, int N, int K){
  __shared__ uint16_t As[128*64];
  __shared__ uint16_t Bs[128*64];
  int t = threadIdx.x;
  int lane = t & 63, w = t >> 6;
  int wr = (w >> 1) * 64, wc = (w & 1) * 64;
  long bm = (long)blockIdx.x * 128;
  long bn = (long)blockIdx.y * 128;
  f4v acc[4][4];
  #pragma unroll
  for (int i=0;i<4;i++){
    #pragma unroll
    for (int jq=0;jq<4;jq++) acc[i][jq] = (f4v){0.f,0.f,0.f,0.f};
  }
  const int nk = K >> 6;
  for (int kt = 0; kt < nk; ++kt){
    const uint16_t* Ag = A + bm * K + kt*64;
    const uint16_t* Bg = B + bn * K + kt*64;
    #pragma unroll
    for (int i=0;i<4;i++){
      int flat = i*256 + t;
      int row = flat >> 3, col = (flat & 7) << 3;
      __builtin_amdgcn_global_load_lds(
        (const GLOBAL_AS void*)(Ag + (long)row*K + col),
        (LDS_AS void*)(As + flat*8), 16, 0, 0);
    }
    #pragma unroll
    for (int i=0;i<4;i++){
      int flat = i*256 + t;
      int row = flat >> 3, col = (flat & 7) << 3;
      __builtin_amdgcn_global_load_lds(
        (const GLOBAL_AS void*)(Bg + (long)row*K + col),
        (LDS_AS void*)(Bs + flat*8), 16, 0, 0);
    }
    __syncthreads();
    #pragma unroll
    for (int kk=0; kk<2; ++kk){
      s8v af[4], bfr[4];
      int kof = kk*32 + (lane>>4)*8;
      #pragma unroll
      for (int mi=0;mi<4;mi++)
        af[mi] = *(const s8v*)(As + (wr + mi*16 + (lane&15))*64 + kof);
      #pragma unroll
      for (int ni=0;ni<4;ni++)
        bfr[ni] = *(const s8v*)(Bs + (wc + ni*16 + (lane&15))*64 + kof);
      #pragma unroll
      for (int mi=0;mi<4;mi++){
        #pragma unroll
        for (int ni=0;ni<4;ni++)
          acc[mi][ni] = __builtin_amdgcn_mfma_f32_16x16x32_bf16(af[mi], bfr[ni], acc[mi][ni], 0,0,0);
      }
    }
    __syncthreads();
  }
  #pragma unroll
  for (int mi=0;mi<4;mi++){
    #pragma unroll
    for (int ni=0;ni<4;ni++){
      long col = bn + wc + ni*16 + (lane & 15);
      #pragma unroll
      for (int r=0;r<4;r++){
        long row = bm + wr + mi*16 + (lane>>4)*4 + r;
        if (OUT_F32) ((float*)Cv)[row*N + col] = acc[mi][ni][r];
        else ((uint16_t*)Cv)[row*N + col] = f2b(acc[mi][ni][r]);
      }
    }
  }
}

// ---------------- fused layer: qkv MFMA + GAT + LN, one frame per block -------
// 512 threads = 8 waves; wave h computes head h's 192 qkv columns.
__global__ __launch_bounds__(512, 2) void layer_kernel(
    const uint16_t* __restrict__ xc_in, const uint16_t* __restrict__ W,
    const uint16_t* __restrict__ aw, const uint16_t* __restrict__ gw,
    const uint16_t* __restrict__ bw, const int* __restrict__ edges,
    const int* __restrict__ elg,
    uint16_t* __restrict__ xc_out, uint16_t* __restrict__ y,
    int E, int ycol, int graph)
{
  __shared__ uint16_t qs[JC*NH*128];   // 49152 B: row j*8+h, q[0:64]|k[64:128]
  __shared__ uint16_t v1s[JC*NH*32];   // 12288 B, chunk-swizzled
  __shared__ uint16_t v2s[JC*NH*32];   // 12288 B, chunk-swizzled
  __shared__ float sexs[EMAX*NH];
  __shared__ float smax[NH];
  __shared__ float awf[64];
  __shared__ int esrc[EMAX], edst[EMAX];
  __shared__ uint16_t glb[2*CH];

  int f = blockIdx.x;
  int t = threadIdx.x;
  int lane = t & 63;
  int h = t >> 6;           // wave id = head

  if (t < 64) awf[t] = b2f(aw[t]);
  if (t >= 64 && t < 320){ int c = t - 64; glb[c] = gw[c]; glb[256+c] = bw[c]; }
  if (t >= 320 && t < 320 + E) esrc[t-320] = edges[t-320];
  if (t >= 320 && t < 320 + E) edst[t-320] = edges[E + t-320];

  // ---- Phase 2: MFMA qkv (A from global xc, B = W streamed from L2) ----
  const uint16_t* Ab = xc_in + ((long)f*JC + (lane & 15))*CH + ((lane>>4)*8);
  const uint16_t* Wb = W + ((long)h*192 + (lane & 15))*CH + ((lane>>4)*8);
  f4v acc[2][12];
  #pragma unroll
  for (int mt=0;mt<2;mt++){
    #pragma unroll
    for (int nt=0;nt<12;nt++) acc[mt][nt] = (f4v){0.f,0.f,0.f,0.f};
  }
  #pragma unroll
  for (int kk=0; kk<8; ++kk){
    s8v a0 = *(const s8v*)(Ab + kk*32);
    s8v a1 = *(const s8v*)(Ab + 16*CH + kk*32);
    #pragma unroll
    for (int nt=0; nt<12; ++nt){
      s8v bf = *(const s8v*)(Wb + nt*16*CH + kk*32);
      acc[0][nt] = __builtin_amdgcn_mfma_f32_16x16x32_bf16(a0, bf, acc[0][nt], 0,0,0);
      acc[1][nt] = __builtin_amdgcn_mfma_f32_16x16x32_bf16(a1, bf, acc[1][nt], 0,0,0);
    }
  }
  // C-write to LDS (rows j<24 only)
  #pragma unroll
  for (int nt=0; nt<12; ++nt){
    #pragma unroll
    for (int mt=0; mt<2; ++mt){
      #pragma unroll
      for (int r=0; r<4; ++r){
        int j = mt*16 + (lane>>4)*4 + r;
        if (j < 24){
          uint16_t val = f2b(acc[mt][nt][r]);
          int row = j*8 + h;
          if (nt < 8){
            qs[row*128 + nt*16 + (lane & 15)] = val;
          } else {
            int d = (nt & 1)*16 + (lane & 15);
            int slot = (d >> 3) ^ ((row >> 1) & 3);
            uint16_t* dp = (nt < 10) ? v1s : v2s;
            dp[row*32 + slot*8 + (d & 7)] = val;
          }
        }
      }
    }
  }
  __syncthreads();

  // ---- Phase 3: edge logits (8 lanes per (e,h)) ----
  float areg[8], aregc[8];
  {
    int ln = t & 7;
    #pragma unroll
    for (int u=0;u<8;u++){
      areg[u] = awf[ln*8 + u];
      aregc[u] = areg[u] * 0.69314718056f;
    }
  }
  const int EN = E * NH;
  for (int base = 0; base < EN*8; base += 512){
    int slot = base + t;
    int item = slot >> 3;
    int ln = slot & 7;
    float s = 0.f;
    if (item < EN){
      int e = item >> 3, hh = item & 7;
      const uint16_t* qp = qs + (esrc[e]*8 + hh)*128 + ln*8;
      const uint16_t* kp = qs + (edst[e]*8 + hh)*128 + 64 + ln*8;
      s8v qv = *(const s8v*)qp;
      s8v kv = *(const s8v*)kp;
      #pragma unroll
      for (int u=0;u<8;u++){
        float xv = b2f((uint16_t)qv[u]) + b2f((uint16_t)kv[u]);
        float e2 = __builtin_amdgcn_exp2f(fabsf(xv) * -1.44269504f);
        float lg = __builtin_amdgcn_logf(1.f + e2);
        s = fmaxf(xv, 0.f) * areg[u] + s;
        s = lg * aregc[u] + s;
      }
    }
    s += __shfl_xor(s, 1, 64);
    s += __shfl_xor(s, 2, 64);
    s += __shfl_xor(s, 4, 64);
    if (item < EN && ln == 0) sexs[item] = s;
  }
  __syncthreads();

  // ---- Phase 4: per-head max (wave 0) ----
  if (t < 64){
    int hh = t & 7;
    float m = -3.4e38f;
    for (int e = t >> 3; e < E; e += 8) m = fmaxf(m, sexs[e*8 + hh]);
    m = fmaxf(m, __shfl_xor(m, 8, 64));
    m = fmaxf(m, __shfl_xor(m, 16, 64));
    m = fmaxf(m, __shfl_xor(m, 32, 64));
    if (t < 8) smax[t] = m;
  }
  __syncthreads();

  // ---- Phase 5: per (j,h) softmax + aggregate + residual + LN ----
  if (t < JC*NH){
    int j = t >> 3, h5 = t & 7;
    int deg = elg[graph*24 + j];
    const int* lst = elg + 48 + (graph*24 + j)*8;
    float mh = smax[h5];
    float ex[8];
    float sig = 1e-10f;
    int el[8];
    #pragma unroll
    for (int i=0;i<8;i++){
      float v = 0.f; int e = 0;
      if (i < deg){ e = lst[i]; v = __builtin_amdgcn_exp2f((sexs[e*8+h5] - mh) * 1.44269504f); }
      el[i] = e; ex[i] = v; sig += v;
    }
    float inv = 1.f / sig;
    float acc5[32];
    #pragma unroll
    for (int d=0;d<32;d++) acc5[d] = 0.f;
    #pragma unroll
    for (int i=0;i<8;i++){
      if (i < deg){
        float wgt = ex[i] * inv;
        int r = edst[el[i]]*8 + h5;
        int sw = (r >> 1) & 3;
        #pragma unroll
        for (int c=0;c<4;c++){
          s8v v = *(const s8v*)(v2s + r*32 + (c ^ sw)*8);
          #pragma unroll
          for (int u=0;u<8;u++) acc5[c*8+u] += wgt * b2f((uint16_t)v[u]);
        }
      }
    }

    int sw1 = (t >> 1) & 3;
    const uint16_t* xp = xc_in + ((long)f*JC)*CH + t*32;
    float pre[32]; float sum = 0.f, sq = 0.f;
    #pragma unroll
    for (int c=0;c<4;c++){
      s8v v1 = *(const s8v*)(v1s + t*32 + (c ^ sw1)*8);
      s8v xv = *(const s8v*)(xp + c*8);
      #pragma unroll
      for (int u=0;u<8;u++){
        float p = b2f((uint16_t)xv[u]) + 0.2f*b2f((uint16_t)v1[u]) + 0.8f*acc5[c*8+u];
        pre[c*8+u] = p; sum += p; sq += p*p;
      }
    }
    #pragma unroll
    for (int m=1;m<8;m<<=1){ sum += __shfl_xor(sum, m, 64); sq += __shfl_xor(sq, m, 64); }
    float mean = sum * (1.f/256.f);
    float var = sq * (1.f/256.f) - mean*mean;
    float rstd = rsqrtf(var + 1e-5f);
    uint16_t* xo = xc_out + ((long)f*JC)*CH + t*32;
    uint16_t* yo = (j < 17) ? (y + (long)(f*17 + j)*K2 + ycol + h5*32) : (uint16_t*)0;
    #pragma unroll
    for (int d0=0; d0<32; d0+=8){
      s8v ov;
      #pragma unroll
      for (int u=0;u<8;u++){
        int c = h5*32 + d0 + u;
        float val = (pre[d0+u]-mean)*rstd*b2f(glb[c]) + b2f(glb[256+c]);
        ov[u] = (short)f2b(val);
      }
      *(s8v*)(xo + d0) = ov;
      if (yo) *(s8v*)(yo + d0) = ov;
    }
  }
}

// ---------------- final bias + LN --------------------------------------------
__global__ __launch_bounds__(256) void final_ln(const float* __restrict__ pre,
    const uint16_t* __restrict__ pb, const uint16_t* __restrict__ gp,
    const uint16_t* __restrict__ bp, const int* __restrict__ flag,
    void* __restrict__ out){
  int row = blockIdx.x*4 + (threadIdx.x>>6);
  int lane = threadIdx.x & 63;
  const float* p = pre + (long)row*CH + lane*4;
  f4v pv = *(const f4v*)p;
  float v[4]; float sum = 0.f, sq = 0.f;
  #pragma unroll
  for (int i=0;i<4;i++){ int c = lane*4+i; v[i] = pv[i] + b2f(pb[c]); sum += v[i]; sq += v[i]*v[i]; }
  #pragma unroll
  for (int m=1;m<64;m<<=1){ sum += __shfl_xor(sum, m, 64); sq += __shfl_xor(sq, m, 64); }
  float mean = sum * (1.f/256.f);
  float var = sq * (1.f/256.f) - mean*mean;
  float rstd = rsqrtf(var + 1e-5f);
  float o[4];
  #pragma unroll
  for (int i=0;i<4;i++){
    int c = lane*4+i;
    o[i] = (v[i]-mean)*rstd*b2f(gp[c]) + b2f(bp[c]);
  }
  if (*flag){
    s4v ov;
    #pragma unroll
    for (int i=0;i<4;i++) ov[i] = (short)f2b(o[i]);
    *(s4v*)((uint16_t*)out + (long)row*CH + lane*4) = ov;
  } else {
    f4v ov;
    #pragma unroll
    for (int i=0;i<4;i++) ov[i] = o[i];
    *(f4v*)((float*)out + (long)row*CH + lane*4) = ov;
  }
}

// ---------------- launch ------------------------------------------------------
extern "C" void kernel_launch(void* const* d_in, const int* in_sizes, int n_in,
                              void* d_out, int out_size, void* d_ws, size_t ws_size,
                              hipStream_t stream){
  const int* eskel = (const int*)d_in[21];
  const int* ecay  = (const int*)d_in[22];

  char* ws = (char*)d_ws;
  const size_t QKV_B  = (size_t)M1 * N1 * 2;
  const size_t XC_B   = (size_t)M1 * CH * 2;
  const size_t Y_B    = (size_t)M2 * K2 * 2;
  const size_t ARENA_OFF = QKV_B + 2*XC_B + Y_B;
  const size_t ARENA_B = 7543808L * 2;
  float*    pre = (float*)ws;
  uint16_t* xcA = (uint16_t*)(ws + QKV_B);
  uint16_t* xcB = (uint16_t*)(ws + QKV_B + XC_B);
  uint16_t* y   = (uint16_t*)(ws + QKV_B + 2*XC_B);
  uint16_t* arena = (uint16_t*)(ws + ARENA_OFF);
  int*      flag  = (int*)(ws + ARENA_OFF + ARENA_B);
  int*      elg   = flag + 16;

  const uint16_t* x_bf = arena;
  const uint16_t* wq[4] = {arena + 5640192, arena + 6033984, arena + 6427776, arena + 6821568};
  const uint16_t* aw[4] = {arena + 6033408, arena + 6427200, arena + 6820992, arena + 7214784};
  const uint16_t* gg[4] = {arena + 6033472, arena + 6427264, arena + 6821056, arena + 7214848};
  const uint16_t* bb[4] = {arena + 6033728, arena + 6427520, arena + 6821312, arena + 7215104};
  const uint16_t* pw = arena + 7215360;
  const uint16_t* pb = arena + 7543040;
  const uint16_t* gp = arena + 7543296;
  const uint16_t* bp = arena + 7543552;

  detect_kernel<<<1, 256, 0, stream>>>((const uint16_t*)d_in[0], flag);

  Ptrs ptrs;
  for (int i = 0; i < 21; i++) ptrs.p[i] = d_in[i];
  convert_kernel<<<3684, 256, 0, stream>>>(ptrs, flag, arena);

  prep_kernel<<<53696, 256, 0, stream>>>(x_bf, xcA, y);
  build_elist<<<1, 64, 0, stream>>>(eskel, ecay, elg);

  uint16_t* xcs[2] = {xcA, xcB};
  for (int L = 0; L < 4; ++L){
    const int* ed = (L & 1) ? ecay : eskel;
    int E = (L & 1) ? 120 : 49;
    layer_kernel<<<F_FRAMES, 512, 0, stream>>>(xcs[L & 1], wq[L], aw[L], gg[L], bb[L],
                                               ed, elg, xcs[(L + 1) & 1], y,
                                               E, (L + 1) * 256, L & 1);
  }
  gemm_bt<1><<<dim3(173, 2), 256, 0, stream>>>(y, pw, pre, M2, N2, K2);
  final_ln<<<5508, 256, 0, stream>>>(pre, pb, gp, bp, flag, d_out);
}

// Round 7
// 545.260 us; speedup vs baseline: 1.7270x; 1.7270x over previous
//
#include <hip/hip_runtime.h>
#include <stdint.h>

#define F_FRAMES 1296
#define JC 24
#define CH 256
#define NH 8
#define EMAX 120
#define M1 31104
#define N1 1536
#define K1 256
#define M2 22144
#define MREAL 22032
#define K2 1280
#define N2 256

typedef __attribute__((ext_vector_type(8))) short s8v;
typedef __attribute__((ext_vector_type(4))) short s4v;
typedef __attribute__((ext_vector_type(4))) float f4v;

#define GLOBAL_AS __attribute__((address_space(1)))
#define LDS_AS __attribute__((address_space(3)))

__device__ __forceinline__ float b2f(uint16_t u){
  union { float f; uint32_t u; } v; v.u = ((uint32_t)u) << 16; return v.f;
}
__device__ __forceinline__ uint16_t f2b(float f){
  union { float f; uint32_t u; } v; v.f = f;
  uint32_t u = v.u;
  uint32_t r = (u + 0x7fffu + ((u >> 16) & 1u)) >> 16;
  return (uint16_t)r;
}

// ---------------- dtype detection -------------------------------------------
__global__ __launch_bounds__(256) void detect_kernel(const uint16_t* __restrict__ x,
                                                     int* __restrict__ flag){
  __shared__ int cnt;
  if (threadIdx.x == 0) cnt = 0;
  __syncthreads();
  int good = 0;
  for (int i = threadIdx.x; i < 512; i += 256){
    uint16_t v = x[i];
    int e = (v >> 7) & 0xFF;
    good += (e >= 115 && e <= 131) ? 1 : 0;
  }
  atomicAdd(&cnt, good);
  __syncthreads();
  if (threadIdx.x == 0) *flag = (cnt >= 400) ? 1 : 0;
}

// ---------------- convert all float inputs into a bf16 arena ----------------
struct Ptrs { const void* p[21]; };

__constant__ int c_off[22] = {
  0, 5640192, 6033408, 6033472, 6033728, 6033984, 6427200, 6427264, 6427520,
  6427776, 6820992, 6821056, 6821312, 6821568, 7214784, 7214848, 7215104,
  7215360, 7543040, 7543296, 7543552, 7543808};

__global__ __launch_bounds__(256) void convert_kernel(Ptrs ptrs,
        const int* __restrict__ flag, uint16_t* __restrict__ arena){
  long base = ((long)blockIdx.x * 256 + threadIdx.x) * 8;
  if (base >= 7543808L) return;
  int seg = 0;
  while (c_off[seg + 1] <= base) seg++;
  long loc = base - c_off[seg];
  if (*flag){
    *(s8v*)(arena + base) = *(const s8v*)((const uint16_t*)ptrs.p[seg] + loc);
  } else {
    const float* s = (const float*)ptrs.p[seg] + loc;
    f4v a = *(const f4v*)s;
    f4v b = *(const f4v*)(s + 4);
    s8v o;
    #pragma unroll
    for (int u = 0; u < 4; u++){ o[u] = (short)f2b(a[u]); o[4+u] = (short)f2b(b[u]); }
    *(s8v*)(arena + base) = o;
  }
}

// ---------------- prep ---------------------------------------------------------
__global__ __launch_bounds__(256) void prep_kernel(const uint16_t* __restrict__ x,
                     uint16_t* __restrict__ xc0, uint16_t* __restrict__ y){
  long i = (long)blockIdx.x * 256 + threadIdx.x;
  const long n1 = (long)F_FRAMES * JC * CH;
  const long n2 = (long)MREAL * CH;
  const long n3 = (long)(M2 - MREAL) * K2;
  if (i < n1){
    long f = i / (JC*CH); long r = i % (JC*CH);
    int j = (int)(r >> 8); int c = (int)(r & 255);
    uint16_t v = 0;
    if (j < 17) v = x[(f*17 + j)*CH + c];
    xc0[i] = v;
  } else if (i < n1 + n2){
    long i2 = i - n1;
    long row = i2 >> 8; int c = (int)(i2 & 255);
    y[row*K2 + c] = x[i2];
  } else if (i < n1 + n2 + n3){
    long i3 = i - n1 - n2;
    long row = MREAL + i3 / K2; int c = (int)(i3 % K2);
    y[row*K2 + c] = 0;
  }
}

// ---------------- build per-src edge lists (once per call) -------------------
__global__ __launch_bounds__(64) void build_elist(const int* __restrict__ eskel,
        const int* __restrict__ ecay, int* __restrict__ out){
  int t = threadIdx.x;
  int g = t >> 5, j = t & 31;
  if (j < 24){
    const int* ed = g ? ecay : eskel;
    int E = g ? 120 : 49;
    int c = 0;
    for (int e = 0; e < E; e++)
      if (ed[e] == j){ out[48 + (g*24 + j)*8 + c] = e; c++; }
    out[g*24 + j] = c;
  }
}

// ---------------- GEMM: 1-D grid, bijective XCD swizzle (m204) ----------------
// wgid/nbn = M-panel, wgid%nbn = N-panel -> the nbn blocks sharing an A-panel
// run contiguously on ONE XCD's L2.
template<int OUT_F32>
__global__ __launch_bounds__(256) void gemm_bt(const uint16_t* __restrict__ A,
        const uint16_t* __restrict__ B, void* __restrict__ Cv,
        int M, int N, int K, int nbn){
  __shared__ uint16_t As[128*64];
  __shared__ uint16_t Bs[128*64];
  int t = threadIdx.x;
  int lane = t & 63, w = t >> 6;
  int wr = (w >> 1) * 64, wc = (w & 1) * 64;

  int total = gridDim.x;
  int q = total >> 3, r = total & 7;
  int orig = blockIdx.x;
  int xcd = orig & 7, loc = orig >> 3;
  int wgid = (xcd < r ? xcd*(q+1) : r*(q+1) + (xcd-r)*q) + loc;
  long bm = (long)(wgid / nbn) * 128;
  long bn = (long)(wgid % nbn) * 128;

  f4v acc[4][4];
  #pragma unroll
  for (int i=0;i<4;i++){
    #pragma unroll
    for (int jq=0;jq<4;jq++) acc[i][jq] = (f4v){0.f,0.f,0.f,0.f};
  }
  const int nk = K >> 6;
  for (int kt = 0; kt < nk; ++kt){
    const uint16_t* Ag = A + bm * K + kt*64;
    const uint16_t* Bg = B + bn * K + kt*64;
    #pragma unroll
    for (int i=0;i<4;i++){
      int flat = i*256 + t;
      int row = flat >> 3, col = (flat & 7) << 3;
      __builtin_amdgcn_global_load_lds(
        (const GLOBAL_AS void*)(Ag + (long)row*K + col),
        (LDS_AS void*)(As + flat*8), 16, 0, 0);
    }
    #pragma unroll
    for (int i=0;i<4;i++){
      int flat = i*256 + t;
      int row = flat >> 3, col = (flat & 7) << 3;
      __builtin_amdgcn_global_load_lds(
        (const GLOBAL_AS void*)(Bg + (long)row*K + col),
        (LDS_AS void*)(Bs + flat*8), 16, 0, 0);
    }
    __syncthreads();
    #pragma unroll
    for (int kk=0; kk<2; ++kk){
      s8v af[4], bfr[4];
      int kof = kk*32 + (lane>>4)*8;
      #pragma unroll
      for (int mi=0;mi<4;mi++)
        af[mi] = *(const s8v*)(As + (wr + mi*16 + (lane&15))*64 + kof);
      #pragma unroll
      for (int ni=0;ni<4;ni++)
        bfr[ni] = *(const s8v*)(Bs + (wc + ni*16 + (lane&15))*64 + kof);
      #pragma unroll
      for (int mi=0;mi<4;mi++){
        #pragma unroll
        for (int ni=0;ni<4;ni++)
          acc[mi][ni] = __builtin_amdgcn_mfma_f32_16x16x32_bf16(af[mi], bfr[ni], acc[mi][ni], 0,0,0);
      }
    }
    __syncthreads();
  }
  #pragma unroll
  for (int mi=0;mi<4;mi++){
    #pragma unroll
    for (int ni=0;ni<4;ni++){
      long col = bn + wc + ni*16 + (lane & 15);
      #pragma unroll
      for (int r2=0;r2<4;r2++){
        long row = bm + wr + mi*16 + (lane>>4)*4 + r2;
        if (OUT_F32) ((float*)Cv)[row*N + col] = acc[mi][ni][r2];
        else ((uint16_t*)Cv)[row*N + col] = f2b(acc[mi][ni][r2]);
      }
    }
  }
}

// ---------------- logit kernel: edge logits, all-LDS, per-frame block ---------
__global__ __launch_bounds__(512) void logit_kernel(
    const uint16_t* __restrict__ qkv, const int* __restrict__ edges,
    const uint16_t* __restrict__ aw, float* __restrict__ sexg, int E)
{
  __shared__ uint16_t qs[JC*NH*128];   // 48 KB, swizzled q|k
  __shared__ float awf[64];
  __shared__ int esrc[EMAX], edst[EMAX];

  int f = blockIdx.x;
  int t = threadIdx.x;
  const uint16_t* qg = qkv + (long)f * JC * N1;

  #pragma unroll
  for (int i=0;i<6;i++){
    int c = i*512 + t;            // 16B granule id, 0..3071
    int row = c >> 4;             // j*8+h
    int j = row >> 3, h = row & 7;
    int ch = c & 15;
    int chp = (ch & 8) | ((ch & 7) ^ h);
    const uint16_t* src = qg + j*N1 + h*192 +
                          ((chp & 8) ? (64 + (chp & 7)*8) : (chp*8));
    __builtin_amdgcn_global_load_lds(
      (const GLOBAL_AS void*)src,
      (LDS_AS void*)(qs + c*8), 16, 0, 0);
  }
  if (t < E){ esrc[t] = edges[t]; edst[t] = edges[E + t]; }
  if (t < 64) awf[t] = b2f(aw[t]);
  __syncthreads();

  float areg[8], aregc[8];
  {
    int ln = t & 7;
    #pragma unroll
    for (int u=0;u<8;u++){
      areg[u] = awf[ln*8 + u];
      aregc[u] = areg[u] * 0.69314718056f;
    }
  }

  const int EN = E * NH;
  for (int base = 0; base < EN*8; base += 512){
    int slot = base + t;
    int item = slot >> 3;
    int ln = slot & 7;
    float s = 0.f;
    if (item < EN){
      int e = item >> 3, h = item & 7;
      int cs = ln ^ h;
      const uint16_t* qp = qs + ((esrc[e]*8 + h)*16 + cs)*8;
      const uint16_t* kp = qs + ((edst[e]*8 + h)*16 + 8 + cs)*8;
      s8v qv = *(const s8v*)qp;
      s8v kv = *(const s8v*)kp;
      #pragma unroll
      for (int u=0;u<8;u++){
        float xv = b2f((uint16_t)qv[u]) + b2f((uint16_t)kv[u]);
        float e2 = __builtin_amdgcn_exp2f(fabsf(xv) * -1.44269504f);
        float lg = __builtin_amdgcn_logf(1.f + e2);
        s = fmaxf(xv, 0.f) * areg[u] + s;
        s = lg * aregc[u] + s;
      }
    }
    s += __shfl_xor(s, 1, 64);
    s += __shfl_xor(s, 2, 64);
    s += __shfl_xor(s, 4, 64);
    if (item < EN && ln == 0) sexg[(long)f*EN + item] = s;
  }
}

// ---------------- gat2: softmax + aggregate + residual + LN ------------------
__global__ __launch_bounds__(256) void gat_kernel(
    const uint16_t* __restrict__ qkv, const uint16_t* __restrict__ xc,
    const int* __restrict__ edges, const float* __restrict__ sexg,
    const int* __restrict__ elg,
    const uint16_t* __restrict__ gw, const uint16_t* __restrict__ bw,
    uint16_t* __restrict__ xc_out, uint16_t* __restrict__ y,
    int E, int ycol, int graph)
{
  __shared__ uint16_t v2s[JC*NH*32];   // 12288 B, swizzled
  __shared__ float sexs[EMAX*NH];
  __shared__ float smax[NH];
  __shared__ int edst[EMAX];
  __shared__ uint16_t glb[2*CH];

  int f = blockIdx.x;
  int t = threadIdx.x;
  const uint16_t* qg = qkv + (long)f * JC * N1;
  const int EN = E * NH;

  #pragma unroll
  for (int i=0;i<3;i++){
    int g = i*256 + t;
    int r = g >> 2, cs = g & 3;
    int c = cs ^ ((r >> 1) & 3);
    int j = r >> 3, h = r & 7;
    const uint16_t* s2 = qg + j*N1 + h*192 + 160 + c*8;
    __builtin_amdgcn_global_load_lds((const GLOBAL_AS void*)s2,
        (LDS_AS void*)(v2s + g*8), 16, 0, 0);
  }
  if (t < E) edst[t] = edges[E + t];
  if (t < (EN >> 2)) ((f4v*)sexs)[t] = ((const f4v*)(sexg + (long)f*EN))[t];
  glb[t] = gw[t]; glb[256 + t] = bw[t];
  __syncthreads();

  if (t < 64){
    int h = t & 7;
    float m = -3.4e38f;
    for (int e = t >> 3; e < E; e += 8) m = fmaxf(m, sexs[e*8 + h]);
    m = fmaxf(m, __shfl_xor(m, 8, 64));
    m = fmaxf(m, __shfl_xor(m, 16, 64));
    m = fmaxf(m, __shfl_xor(m, 32, 64));
    if (t < 8) smax[t] = m;
  }
  __syncthreads();

  if (t < JC*NH){
    int j = t >> 3, h = t & 7;
    int deg = elg[graph*24 + j];
    const int* lst = elg + 48 + (graph*24 + j)*8;
    float mh = smax[h];
    float ex[8];
    float sig = 1e-10f;
    int el[8];
    #pragma unroll
    for (int i=0;i<8;i++){
      float v = 0.f; int e = 0;
      if (i < deg){ e = lst[i]; v = __builtin_amdgcn_exp2f((sexs[e*8+h] - mh) * 1.44269504f); }
      el[i] = e; ex[i] = v; sig += v;
    }
    float inv = 1.f / sig;
    float acc[32];
    #pragma unroll
    for (int d=0;d<32;d++) acc[d] = 0.f;
    #pragma unroll
    for (int i=0;i<8;i++){
      if (i < deg){
        float wgt = ex[i] * inv;
        int r = edst[el[i]]*8 + h;
        int sw = (r >> 1) & 3;
        #pragma unroll
        for (int c=0;c<4;c++){
          s8v v = *(const s8v*)(v2s + r*32 + (c ^ sw)*8);
          #pragma unroll
          for (int u=0;u<8;u++) acc[c*8+u] += wgt * b2f((uint16_t)v[u]);
        }
      }
    }

    const uint16_t* v1p = qg + j*N1 + h*192 + 128;
    const uint16_t* xp = xc + (long)f*JC*CH + t*32;
    float pre[32]; float sum = 0.f, sq = 0.f;
    #pragma unroll
    for (int c=0;c<4;c++){
      s8v v1 = *(const s8v*)(v1p + c*8);
      s8v xv = *(const s8v*)(xp + c*8);
      #pragma unroll
      for (int u=0;u<8;u++){
        float p = b2f((uint16_t)xv[u]) + 0.2f*b2f((uint16_t)v1[u]) + 0.8f*acc[c*8+u];
        pre[c*8+u] = p; sum += p; sq += p*p;
      }
    }
    #pragma unroll
    for (int m=1;m<8;m<<=1){ sum += __shfl_xor(sum, m, 64); sq += __shfl_xor(sq, m, 64); }
    float mean = sum * (1.f/256.f);
    float var = sq * (1.f/256.f) - mean*mean;
    float rstd = rsqrtf(var + 1e-5f);
    uint16_t* xo = xc_out + (long)f*JC*CH + t*32;
    uint16_t* yo = (j < 17) ? (y + (long)(f*17 + j)*K2 + ycol + h*32) : (uint16_t*)0;
    #pragma unroll
    for (int d0=0; d0<32; d0+=8){
      s8v ov;
      #pragma unroll
      for (int u=0;u<8;u++){
        int c = h*32 + d0 + u;
        float val = (pre[d0+u]-mean)*rstd*b2f(glb[c]) + b2f(glb[256+c]);
        ov[u] = (short)f2b(val);
      }
      *(s8v*)(xo + d0) = ov;
      if (yo) *(s8v*)(yo + d0) = ov;
    }
  }
}

// ---------------- final bias + LN --------------------------------------------
__global__ __launch_bounds__(256) void final_ln(const float* __restrict__ pre,
    const uint16_t* __restrict__ pb, const uint16_t* __restrict__ gp,
    const uint16_t* __restrict__ bp, const int* __restrict__ flag,
    void* __restrict__ out){
  int row = blockIdx.x*4 + (threadIdx.x>>6);
  int lane = threadIdx.x & 63;
  const float* p = pre + (long)row*CH + lane*4;
  f4v pv = *(const f4v*)p;
  float v[4]; float sum = 0.f, sq = 0.f;
  #pragma unroll
  for (int i=0;i<4;i++){ int c = lane*4+i; v[i] = pv[i] + b2f(pb[c]); sum += v[i]; sq += v[i]*v[i]; }
  #pragma unroll
  for (int m=1;m<64;m<<=1){ sum += __shfl_xor(sum, m, 64); sq += __shfl_xor(sq, m, 64); }
  float mean = sum * (1.f/256.f);
  float var = sq * (1.f/256.f) - mean*mean;
  float rstd = rsqrtf(var + 1e-5f);
  float o[4];
  #pragma unroll
  for (int i=0;i<4;i++){
    int c = lane*4+i;
    o[i] = (v[i]-mean)*rstd*b2f(gp[c]) + b2f(bp[c]);
  }
  if (*flag){
    s4v ov;
    #pragma unroll
    for (int i=0;i<4;i++) ov[i] = (short)f2b(o[i]);
    *(s4v*)((uint16_t*)out + (long)row*CH + lane*4) = ov;
  } else {
    f4v ov;
    #pragma unroll
    for (int i=0;i<4;i++) ov[i] = o[i];
    *(f4v*)((float*)out + (long)row*CH + lane*4) = ov;
  }
}

// ---------------- launch ------------------------------------------------------
extern "C" void kernel_launch(void* const* d_in, const int* in_sizes, int n_in,
                              void* d_out, int out_size, void* d_ws, size_t ws_size,
                              hipStream_t stream){
  const int* eskel = (const int*)d_in[21];
  const int* ecay  = (const int*)d_in[22];

  char* ws = (char*)d_ws;
  const size_t QKV_B  = (size_t)M1 * N1 * 2;
  const size_t XC_B   = (size_t)M1 * CH * 2;
  const size_t Y_B    = (size_t)M2 * K2 * 2;
  const size_t ARENA_OFF = QKV_B + 2*XC_B + Y_B;
  const size_t ARENA_B = 7543808L * 2;
  uint16_t* qkv = (uint16_t*)ws;
  float*    pre = (float*)ws;
  uint16_t* xcA = (uint16_t*)(ws + QKV_B);
  uint16_t* xcB = (uint16_t*)(ws + QKV_B + XC_B);
  uint16_t* y   = (uint16_t*)(ws + QKV_B + 2*XC_B);
  uint16_t* arena = (uint16_t*)(ws + ARENA_OFF);
  int*      flag  = (int*)(ws + ARENA_OFF + ARENA_B);
  int*      elg   = flag + 16;
  float*    sexg  = (float*)arena;             // overlays x (dead after prep)

  const uint16_t* x_bf = arena;
  const uint16_t* wq[4] = {arena + 5640192, arena + 6033984, arena + 6427776, arena + 6821568};
  const uint16_t* aw[4] = {arena + 6033408, arena + 6427200, arena + 6820992, arena + 7214784};
  const uint16_t* gg[4] = {arena + 6033472, arena + 6427264, arena + 6821056, arena + 7214848};
  const uint16_t* bb[4] = {arena + 6033728, arena + 6427520, arena + 6821312, arena + 7215104};
  const uint16_t* pw = arena + 7215360;
  const uint16_t* pb = arena + 7543040;
  const uint16_t* gp = arena + 7543296;
  const uint16_t* bp = arena + 7543552;

  detect_kernel<<<1, 256, 0, stream>>>((const uint16_t*)d_in[0], flag);

  Ptrs ptrs;
  for (int i = 0; i < 21; i++) ptrs.p[i] = d_in[i];
  convert_kernel<<<3684, 256, 0, stream>>>(ptrs, flag, arena);

  prep_kernel<<<53696, 256, 0, stream>>>(x_bf, xcA, y);
  build_elist<<<1, 64, 0, stream>>>(eskel, ecay, elg);

  uint16_t* xcs[2] = {xcA, xcB};
  for (int L = 0; L < 4; ++L){
    gemm_bt<0><<<2916, 256, 0, stream>>>(xcs[L & 1], wq[L], qkv, M1, N1, K1, 12);
    const int* ed = (L & 1) ? ecay : eskel;
    int E = (L & 1) ? 120 : 49;
    logit_kernel<<<F_FRAMES, 512, 0, stream>>>(qkv, ed, aw[L], sexg, E);
    gat_kernel<<<F_FRAMES, 256, 0, stream>>>(qkv, xcs[L & 1], ed, sexg, elg,
                                             gg[L], bb[L],
                                             xcs[(L + 1) & 1], y, E, (L + 1) * 256, L & 1);
  }
  gemm_bt<1><<<346, 256, 0, stream>>>(y, pw, pre, M2, N2, K2, 2);
  final_ln<<<5508, 256, 0, stream>>>(pre, pb, gp, bp, flag, d_out);
}

// Round 8
// 542.121 us; speedup vs baseline: 1.7370x; 1.0058x over previous
//
#include <hip/hip_runtime.h>
#include <stdint.h>

#define F_FRAMES 1296
#define JC 24
#define CH 256
#define NH 8
#define EMAX 120
#define M1 31104
#define N1 1536
#define K1 256
#define M2 22144
#define MREAL 22032
#define K2 1280
#define N2 256

typedef __attribute__((ext_vector_type(8))) short s8v;
typedef __attribute__((ext_vector_type(4))) short s4v;
typedef __attribute__((ext_vector_type(4))) float f4v;

#define GLOBAL_AS __attribute__((address_space(1)))
#define LDS_AS __attribute__((address_space(3)))

__device__ __forceinline__ float b2f(uint16_t u){
  union { float f; uint32_t u; } v; v.u = ((uint32_t)u) << 16; return v.f;
}
__device__ __forceinline__ uint16_t f2b(float f){
  union { float f; uint32_t u; } v; v.f = f;
  uint32_t u = v.u;
  uint32_t r = (u + 0x7fffu + ((u >> 16) & 1u)) >> 16;
  return (uint16_t)r;
}

// ---------------- dtype detection -------------------------------------------
__global__ __launch_bounds__(256) void detect_kernel(const uint16_t* __restrict__ x,
                                                     int* __restrict__ flag){
  __shared__ int cnt;
  if (threadIdx.x == 0) cnt = 0;
  __syncthreads();
  int good = 0;
  for (int i = threadIdx.x; i < 512; i += 256){
    uint16_t v = x[i];
    int e = (v >> 7) & 0xFF;
    good += (e >= 115 && e <= 131) ? 1 : 0;
  }
  atomicAdd(&cnt, good);
  __syncthreads();
  if (threadIdx.x == 0) *flag = (cnt >= 400) ? 1 : 0;
}

// ---------------- convert all float inputs into a bf16 arena ----------------
struct Ptrs { const void* p[21]; };

__constant__ int c_off[22] = {
  0, 5640192, 6033408, 6033472, 6033728, 6033984, 6427200, 6427264, 6427520,
  6427776, 6820992, 6821056, 6821312, 6821568, 7214784, 7214848, 7215104,
  7215360, 7543040, 7543296, 7543552, 7543808};

__global__ __launch_bounds__(256) void convert_kernel(Ptrs ptrs,
        const int* __restrict__ flag, uint16_t* __restrict__ arena){
  long base = ((long)blockIdx.x * 256 + threadIdx.x) * 8;
  if (base >= 7543808L) return;
  int seg = 0;
  while (c_off[seg + 1] <= base) seg++;
  long loc = base - c_off[seg];
  if (*flag){
    *(s8v*)(arena + base) = *(const s8v*)((const uint16_t*)ptrs.p[seg] + loc);
  } else {
    const float* s = (const float*)ptrs.p[seg] + loc;
    f4v a = *(const f4v*)s;
    f4v b = *(const f4v*)(s + 4);
    s8v o;
    #pragma unroll
    for (int u = 0; u < 4; u++){ o[u] = (short)f2b(a[u]); o[4+u] = (short)f2b(b[u]); }
    *(s8v*)(arena + base) = o;
  }
}

// ---------------- prep ---------------------------------------------------------
__global__ __launch_bounds__(256) void prep_kernel(const uint16_t* __restrict__ x,
                     uint16_t* __restrict__ xc0, uint16_t* __restrict__ y){
  long i = (long)blockIdx.x * 256 + threadIdx.x;
  const long n1 = (long)F_FRAMES * JC * CH;
  const long n2 = (long)MREAL * CH;
  const long n3 = (long)(M2 - MREAL) * K2;
  if (i < n1){
    long f = i / (JC*CH); long r = i % (JC*CH);
    int j = (int)(r >> 8); int c = (int)(r & 255);
    uint16_t v = 0;
    if (j < 17) v = x[(f*17 + j)*CH + c];
    xc0[i] = v;
  } else if (i < n1 + n2){
    long i2 = i - n1;
    long row = i2 >> 8; int c = (int)(i2 & 255);
    y[row*K2 + c] = x[i2];
  } else if (i < n1 + n2 + n3){
    long i3 = i - n1 - n2;
    long row = MREAL + i3 / K2; int c = (int)(i3 % K2);
    y[row*K2 + c] = 0;
  }
}

// ---------------- build per-src edge lists (once per call) -------------------
__global__ __launch_bounds__(64) void build_elist(const int* __restrict__ eskel,
        const int* __restrict__ ecay, int* __restrict__ out){
  int t = threadIdx.x;
  int g = t >> 5, j = t & 31;
  if (j < 24){
    const int* ed = g ? ecay : eskel;
    int E = g ? 120 : 49;
    int c = 0;
    for (int e = 0; e < E; e++)
      if (ed[e] == j){ out[48 + (g*24 + j)*8 + c] = e; c++; }
    out[g*24 + j] = c;
  }
}

// ---------------- wv_copy: gather v-rows of all 4 W's into [512][256] --------
struct WPtrs { const uint16_t* w[4]; };
__global__ __launch_bounds__(256) void wv_copy(WPtrs wp, uint16_t* __restrict__ wv){
  int g = blockIdx.x * 256 + threadIdx.x;      // granule of 8, total 65536
  int L = g >> 14;                              // 16384 granules per layer
  int loc = g & 16383;
  int row = loc >> 5;                           // 0..511
  int col = (loc & 31) * 8;
  int wrow = (row >> 6) * 192 + 128 + (row & 63);
  *(s8v*)(wv + ((long)L*512 + row)*256 + col) =
      *(const s8v*)(wp.w[L] + (long)wrow*256 + col);
}

// ---------------- GEMM: 1-D grid, bijective XCD swizzle (m204) ----------------
template<int OUT_F32>
__global__ __launch_bounds__(256) void gemm_bt(const uint16_t* __restrict__ A,
        const uint16_t* __restrict__ B, void* __restrict__ Cv,
        int M, int N, int K, int nbn){
  __shared__ uint16_t As[128*64];
  __shared__ uint16_t Bs[128*64];
  int t = threadIdx.x;
  int lane = t & 63, w = t >> 6;
  int wr = (w >> 1) * 64, wc = (w & 1) * 64;

  int total = gridDim.x;
  int q = total >> 3, r = total & 7;
  int orig = blockIdx.x;
  int xcd = orig & 7, loc = orig >> 3;
  int wgid = (xcd < r ? xcd*(q+1) : r*(q+1) + (xcd-r)*q) + loc;
  long bm = (long)(wgid / nbn) * 128;
  long bn = (long)(wgid % nbn) * 128;

  f4v acc[4][4];
  #pragma unroll
  for (int i=0;i<4;i++){
    #pragma unroll
    for (int jq=0;jq<4;jq++) acc[i][jq] = (f4v){0.f,0.f,0.f,0.f};
  }
  const int nk = K >> 6;
  for (int kt = 0; kt < nk; ++kt){
    const uint16_t* Ag = A + bm * K + kt*64;
    const uint16_t* Bg = B + bn * K + kt*64;
    #pragma unroll
    for (int i=0;i<4;i++){
      int flat = i*256 + t;
      int row = flat >> 3, col = (flat & 7) << 3;
      __builtin_amdgcn_global_load_lds(
        (const GLOBAL_AS void*)(Ag + (long)row*K + col),
        (LDS_AS void*)(As + flat*8), 16, 0, 0);
    }
    #pragma unroll
    for (int i=0;i<4;i++){
      int flat = i*256 + t;
      int row = flat >> 3, col = (flat & 7) << 3;
      __builtin_amdgcn_global_load_lds(
        (const GLOBAL_AS void*)(Bg + (long)row*K + col),
        (LDS_AS void*)(Bs + flat*8), 16, 0, 0);
    }
    __syncthreads();
    #pragma unroll
    for (int kk=0; kk<2; ++kk){
      s8v af[4], bfr[4];
      int kof = kk*32 + (lane>>4)*8;
      #pragma unroll
      for (int mi=0;mi<4;mi++)
        af[mi] = *(const s8v*)(As + (wr + mi*16 + (lane&15))*64 + kof);
      #pragma unroll
      for (int ni=0;ni<4;ni++)
        bfr[ni] = *(const s8v*)(Bs + (wc + ni*16 + (lane&15))*64 + kof);
      #pragma unroll
      for (int mi=0;mi<4;mi++){
        #pragma unroll
        for (int ni=0;ni<4;ni++)
          acc[mi][ni] = __builtin_amdgcn_mfma_f32_16x16x32_bf16(af[mi], bfr[ni], acc[mi][ni], 0,0,0);
      }
    }
    __syncthreads();
  }
  #pragma unroll
  for (int mi=0;mi<4;mi++){
    #pragma unroll
    for (int ni=0;ni<4;ni++){
      long col = bn + wc + ni*16 + (lane & 15);
      #pragma unroll
      for (int r2=0;r2<4;r2++){
        long row = bm + wr + mi*16 + (lane>>4)*4 + r2;
        if (OUT_F32) ((float*)Cv)[row*N + col] = acc[mi][ni][r2];
        else ((uint16_t*)Cv)[row*N + col] = f2b(acc[mi][ni][r2]);
      }
    }
  }
}

// ---------------- qk GEMM + fused logits (q,k never hit HBM) ------------------
// Block: M=96 rows (4 frames), N=128 (head h's q|k), K=256. 256 thr = 4 waves.
__global__ __launch_bounds__(256) void qk_logit(
    const uint16_t* __restrict__ xc_in, const uint16_t* __restrict__ W,
    const uint16_t* __restrict__ aw, const int* __restrict__ edges,
    float* __restrict__ sexg, int E)
{
  __shared__ uint16_t AB[14336];    // As[0:6144] Bs[6144:14336]; qs reuses [0:12288]
  __shared__ float awf[64];
  __shared__ int esrc[EMAX], edst[EMAX];

  int t = threadIdx.x;
  int lane = t & 63, w = t >> 6;
  int wr = w >> 1, wc = w & 1;

  int orig = blockIdx.x;                 // 2592 = 8*324, divisible
  int wgid = (orig & 7) * 324 + (orig >> 3);
  int mp = wgid >> 3;                    // M panel (4 frames)
  int h  = wgid & 7;                     // head

  if (t < E){ esrc[t] = edges[t]; edst[t] = edges[E+t]; }
  if (t >= 128 && t < 192) awf[t-128] = b2f(aw[t-128]);

  uint16_t* As = AB;
  uint16_t* Bs = AB + 6144;
  const uint16_t* Ag0 = xc_in + (long)mp*96*256;
  const uint16_t* Bg0 = W + (long)h*192*256;

  f4v acc[3][4];
  #pragma unroll
  for (int i=0;i<3;i++){
    #pragma unroll
    for (int jq=0;jq<4;jq++) acc[i][jq] = (f4v){0.f,0.f,0.f,0.f};
  }

  for (int kt = 0; kt < 4; ++kt){
    #pragma unroll
    for (int i=0;i<3;i++){
      int g = i*256 + t;                 // 768 granules A
      int row = g >> 3, col = (g & 7) << 3;
      __builtin_amdgcn_global_load_lds(
        (const GLOBAL_AS void*)(Ag0 + (long)row*256 + kt*64 + col),
        (LDS_AS void*)(As + g*8), 16, 0, 0);
    }
    #pragma unroll
    for (int i=0;i<4;i++){
      int g = i*256 + t;                 // 1024 granules B
      int row = g >> 3, col = (g & 7) << 3;
      __builtin_amdgcn_global_load_lds(
        (const GLOBAL_AS void*)(Bg0 + (long)row*256 + kt*64 + col),
        (LDS_AS void*)(Bs + g*8), 16, 0, 0);
    }
    __syncthreads();
    #pragma unroll
    for (int kk=0; kk<2; ++kk){
      s8v af[3], bfr[4];
      int kof = kk*32 + (lane>>4)*8;
      #pragma unroll
      for (int mi=0;mi<3;mi++)
        af[mi] = *(const s8v*)(As + (wr*48 + mi*16 + (lane&15))*64 + kof);
      #pragma unroll
      for (int ni=0;ni<4;ni++)
        bfr[ni] = *(const s8v*)(Bs + (wc*64 + ni*16 + (lane&15))*64 + kof);
      #pragma unroll
      for (int mi=0;mi<3;mi++){
        #pragma unroll
        for (int ni=0;ni<4;ni++)
          acc[mi][ni] = __builtin_amdgcn_mfma_f32_16x16x32_bf16(af[mi], bfr[ni], acc[mi][ni], 0,0,0);
      }
    }
    __syncthreads();
  }

  // C -> LDS qs[96][128], 16B-chunk XOR swizzle by row
  uint16_t* qs = AB;
  #pragma unroll
  for (int mi=0;mi<3;mi++){
    #pragma unroll
    for (int ni=0;ni<4;ni++){
      int col = wc*64 + ni*16 + (lane & 15);
      int ch = col >> 3;
      #pragma unroll
      for (int r2=0;r2<4;r2++){
        int row = wr*48 + mi*16 + (lane>>4)*4 + r2;
        int pch = (ch & 8) | ((ch ^ row) & 7);
        qs[row*128 + pch*8 + (col & 7)] = f2b(acc[mi][ni][r2]);
      }
    }
  }
  __syncthreads();

  // logits: items = 4 frames x E edges, 8 lanes per item
  float areg[8], aregc[8];
  {
    int ln = t & 7;
    #pragma unroll
    for (int u=0;u<8;u++){
      areg[u] = awf[ln*8 + u];
      aregc[u] = areg[u] * 0.69314718056f;
    }
  }
  const int items = 4*E;
  for (int base = 0; base < items*8; base += 256){
    int slot = base + t;
    int item = slot >> 3;
    int ln = slot & 7;
    float s = 0.f;
    int fl = 0, e = 0;
    if (item < items){
      fl = item / E; e = item - fl*E;
      int rs = fl*24 + esrc[e];
      int rd = fl*24 + edst[e];
      const uint16_t* qp = qs + rs*128 + ((ln ^ rs) & 7)*8;
      const uint16_t* kp = qs + rd*128 + (8 | ((ln ^ rd) & 7))*8;
      s8v qv = *(const s8v*)qp;
      s8v kv = *(const s8v*)kp;
      #pragma unroll
      for (int u=0;u<8;u++){
        float xv = b2f((uint16_t)qv[u]) + b2f((uint16_t)kv[u]);
        float e2 = __builtin_amdgcn_exp2f(fabsf(xv) * -1.44269504f);
        float lg = __builtin_amdgcn_logf(1.f + e2);
        s = fmaxf(xv, 0.f) * areg[u] + s;
        s = lg * aregc[u] + s;
      }
    }
    s += __shfl_xor(s, 1, 64);
    s += __shfl_xor(s, 2, 64);
    s += __shfl_xor(s, 4, 64);
    if (item < items && ln == 0)
      sexg[((long)mp*4 + fl)*(E*NH) + e*NH + h] = s;
  }
}

// ---------------- gat: softmax + aggregate + residual + LN -------------------
__global__ __launch_bounds__(256) void gat_kernel(
    const uint16_t* __restrict__ vg, const uint16_t* __restrict__ xc,
    const int* __restrict__ edges, const float* __restrict__ sexg,
    const int* __restrict__ elg,
    const uint16_t* __restrict__ gw, const uint16_t* __restrict__ bw,
    uint16_t* __restrict__ xc_out, uint16_t* __restrict__ y,
    int E, int ycol, int graph)
{
  __shared__ uint16_t v2s[JC*NH*32];   // 12288 B, swizzled
  __shared__ float sexs[EMAX*NH];
  __shared__ float smax[NH];
  __shared__ int edst[EMAX];
  __shared__ uint16_t glb[2*CH];

  int f = blockIdx.x;
  int t = threadIdx.x;
  const uint16_t* vf = vg + (long)f * JC * 512;
  const int EN = E * NH;

  #pragma unroll
  for (int i=0;i<3;i++){
    int g = i*256 + t;
    int r = g >> 2, cs = g & 3;
    int c = cs ^ ((r >> 1) & 3);
    int j = r >> 3, h = r & 7;
    const uint16_t* s2 = vf + j*512 + h*64 + 32 + c*8;
    __builtin_amdgcn_global_load_lds((const GLOBAL_AS void*)s2,
        (LDS_AS void*)(v2s + g*8), 16, 0, 0);
  }
  if (t < E) edst[t] = edges[E + t];
  if (t < (EN >> 2)) ((f4v*)sexs)[t] = ((const f4v*)(sexg + (long)f*EN))[t];
  glb[t] = gw[t]; glb[256 + t] = bw[t];
  __syncthreads();

  if (t < 64){
    int h = t & 7;
    float m = -3.4e38f;
    for (int e = t >> 3; e < E; e += 8) m = fmaxf(m, sexs[e*8 + h]);
    m = fmaxf(m, __shfl_xor(m, 8, 64));
    m = fmaxf(m, __shfl_xor(m, 16, 64));
    m = fmaxf(m, __shfl_xor(m, 32, 64));
    if (t < 8) smax[t] = m;
  }
  __syncthreads();

  if (t < JC*NH){
    int j = t >> 3, h = t & 7;
    int deg = elg[graph*24 + j];
    const int* lst = elg + 48 + (graph*24 + j)*8;
    float mh = smax[h];
    float ex[8];
    float sig = 1e-10f;
    int el[8];
    #pragma unroll
    for (int i=0;i<8;i++){
      float v = 0.f; int e = 0;
      if (i < deg){ e = lst[i]; v = __builtin_amdgcn_exp2f((sexs[e*8+h] - mh) * 1.44269504f); }
      el[i] = e; ex[i] = v; sig += v;
    }
    float inv = 1.f / sig;
    float acc[32];
    #pragma unroll
    for (int d=0;d<32;d++) acc[d] = 0.f;
    #pragma unroll
    for (int i=0;i<8;i++){
      if (i < deg){
        float wgt = ex[i] * inv;
        int r = edst[el[i]]*8 + h;
        int sw = (r >> 1) & 3;
        #pragma unroll
        for (int c=0;c<4;c++){
          s8v v = *(const s8v*)(v2s + r*32 + (c ^ sw)*8);
          #pragma unroll
          for (int u=0;u<8;u++) acc[c*8+u] += wgt * b2f((uint16_t)v[u]);
        }
      }
    }

    const uint16_t* v1p = vf + j*512 + h*64;
    const uint16_t* xp = xc + (long)f*JC*CH + t*32;
    float pre[32]; float sum = 0.f, sq = 0.f;
    #pragma unroll
    for (int c=0;c<4;c++){
      s8v v1 = *(const s8v*)(v1p + c*8);
      s8v xv = *(const s8v*)(xp + c*8);
      #pragma unroll
      for (int u=0;u<8;u++){
        float p = b2f((uint16_t)xv[u]) + 0.2f*b2f((uint16_t)v1[u]) + 0.8f*acc[c*8+u];
        pre[c*8+u] = p; sum += p; sq += p*p;
      }
    }
    #pragma unroll
    for (int m=1;m<8;m<<=1){ sum += __shfl_xor(sum, m, 64); sq += __shfl_xor(sq, m, 64); }
    float mean = sum * (1.f/256.f);
    float var = sq * (1.f/256.f) - mean*mean;
    float rstd = rsqrtf(var + 1e-5f);
    uint16_t* xo = xc_out + (long)f*JC*CH + t*32;
    uint16_t* yo = (j < 17) ? (y + (long)(f*17 + j)*K2 + ycol + h*32) : (uint16_t*)0;
    #pragma unroll
    for (int d0=0; d0<32; d0+=8){
      s8v ov;
      #pragma unroll
      for (int u=0;u<8;u++){
        int c = h*32 + d0 + u;
        float val = (pre[d0+u]-mean)*rstd*b2f(glb[c]) + b2f(glb[256+c]);
        ov[u] = (short)f2b(val);
      }
      *(s8v*)(xo + d0) = ov;
      if (yo) *(s8v*)(yo + d0) = ov;
    }
  }
}

// ---------------- final bias + LN --------------------------------------------
__global__ __launch_bounds__(256) void final_ln(const float* __restrict__ pre,
    const uint16_t* __restrict__ pb, const uint16_t* __restrict__ gp,
    const uint16_t* __restrict__ bp, const int* __restrict__ flag,
    void* __restrict__ out){
  int row = blockIdx.x*4 + (threadIdx.x>>6);
  int lane = threadIdx.x & 63;
  const float* p = pre + (long)row*CH + lane*4;
  f4v pv = *(const f4v*)p;
  float v[4]; float sum = 0.f, sq = 0.f;
  #pragma unroll
  for (int i=0;i<4;i++){ int c = lane*4+i; v[i] = pv[i] + b2f(pb[c]); sum += v[i]; sq += v[i]*v[i]; }
  #pragma unroll
  for (int m=1;m<64;m<<=1){ sum += __shfl_xor(sum, m, 64); sq += __shfl_xor(sq, m, 64); }
  float mean = sum * (1.f/256.f);
  float var = sq * (1.f/256.f) - mean*mean;
  float rstd = rsqrtf(var + 1e-5f);
  float o[4];
  #pragma unroll
  for (int i=0;i<4;i++){
    int c = lane*4+i;
    o[i] = (v[i]-mean)*rstd*b2f(gp[c]) + b2f(bp[c]);
  }
  if (*flag){
    s4v ov;
    #pragma unroll
    for (int i=0;i<4;i++) ov[i] = (short)f2b(o[i]);
    *(s4v*)((uint16_t*)out + (long)row*CH + lane*4) = ov;
  } else {
    f4v ov;
    #pragma unroll
    for (int i=0;i<4;i++) ov[i] = o[i];
    *(f4v*)((float*)out + (long)row*CH + lane*4) = ov;
  }
}

// ---------------- launch ------------------------------------------------------
extern "C" void kernel_launch(void* const* d_in, const int* in_sizes, int n_in,
                              void* d_out, int out_size, void* d_ws, size_t ws_size,
                              hipStream_t stream){
  const int* eskel = (const int*)d_in[21];
  const int* ecay  = (const int*)d_in[22];

  char* ws = (char*)d_ws;
  const size_t QKV_B  = (size_t)M1 * N1 * 2;     // big region: vout / pre
  const size_t XC_B   = (size_t)M1 * CH * 2;
  const size_t Y_B    = (size_t)M2 * K2 * 2;
  const size_t ARENA_OFF = QKV_B + 2*XC_B + Y_B;
  const size_t ARENA_B = 7543808L * 2;
  uint16_t* vout = (uint16_t*)ws;                // [M1][512], 32MB
  float*    pre  = (float*)ws;                   // final proj f32, reuses
  uint16_t* xcA = (uint16_t*)(ws + QKV_B);
  uint16_t* xcB = (uint16_t*)(ws + QKV_B + XC_B);
  uint16_t* y   = (uint16_t*)(ws + QKV_B + 2*XC_B);
  uint16_t* arena = (uint16_t*)(ws + ARENA_OFF);
  int*      flag  = (int*)(ws + ARENA_OFF + ARENA_B);
  int*      elg   = flag + 16;
  uint16_t* wv    = (uint16_t*)(ws + ARENA_OFF + ARENA_B + 4096); // 4x512x256 bf16
  float*    sexg  = (float*)arena;               // overlays x (dead after prep)

  const uint16_t* x_bf = arena;
  const uint16_t* wq[4] = {arena + 5640192, arena + 6033984, arena + 6427776, arena + 6821568};
  const uint16_t* aw[4] = {arena + 6033408, arena + 6427200, arena + 6820992, arena + 7214784};
  const uint16_t* gg[4] = {arena + 6033472, arena + 6427264, arena + 6821056, arena + 7214848};
  const uint16_t* bb[4] = {arena + 6033728, arena + 6427520, arena + 6821312, arena + 7215104};
  const uint16_t* pw = arena + 7215360;
  const uint16_t* pb = arena + 7543040;
  const uint16_t* gp = arena + 7543296;
  const uint16_t* bp = arena + 7543552;

  detect_kernel<<<1, 256, 0, stream>>>((const uint16_t*)d_in[0], flag);

  Ptrs ptrs;
  for (int i = 0; i < 21; i++) ptrs.p[i] = d_in[i];
  convert_kernel<<<3684, 256, 0, stream>>>(ptrs, flag, arena);

  prep_kernel<<<53696, 256, 0, stream>>>(x_bf, xcA, y);
  build_elist<<<1, 64, 0, stream>>>(eskel, ecay, elg);

  WPtrs wp = {{wq[0], wq[1], wq[2], wq[3]}};
  wv_copy<<<256, 256, 0, stream>>>(wp, wv);

  uint16_t* xcs[2] = {xcA, xcB};
  for (int L = 0; L < 4; ++L){
    const int* ed = (L & 1) ? ecay : eskel;
    int E = (L & 1) ? 120 : 49;
    qk_logit<<<2592, 256, 0, stream>>>(xcs[L & 1], wq[L], aw[L], ed, sexg, E);
    gemm_bt<0><<<972, 256, 0, stream>>>(xcs[L & 1], wv + (long)L*512*256, vout,
                                        M1, 512, K1, 4);
    gat_kernel<<<F_FRAMES, 256, 0, stream>>>(vout, xcs[L & 1], ed, sexg, elg,
                                             gg[L], bb[L],
                                             xcs[(L + 1) & 1], y, E, (L + 1) * 256, L & 1);
  }
  gemm_bt<1><<<346, 256, 0, stream>>>(y, pw, pre, M2, N2, K2, 2);
  final_ln<<<5508, 256, 0, stream>>>(pre, pb, gp, bp, flag, d_out);
}

// Round 9
// 479.501 us; speedup vs baseline: 1.9638x; 1.1306x over previous
//
#include <hip/hip_runtime.h>
#include <stdint.h>

#define F_FRAMES 1296
#define JC 24
#define CH 256
#define NH 8
#define EMAX 120
#define M1 31104
#define N1 1536
#define K1 256
#define M2 22144
#define MREAL 22032
#define K2 1280
#define N2 256

typedef __attribute__((ext_vector_type(8))) short s8v;
typedef __attribute__((ext_vector_type(4))) short s4v;
typedef __attribute__((ext_vector_type(4))) float f4v;

#define GLOBAL_AS __attribute__((address_space(1)))
#define LDS_AS __attribute__((address_space(3)))

__device__ __forceinline__ float b2f(uint16_t u){
  union { float f; uint32_t u; } v; v.u = ((uint32_t)u) << 16; return v.f;
}
__device__ __forceinline__ uint16_t f2b(float f){
  union { float f; uint32_t u; } v; v.f = f;
  uint32_t u = v.u;
  uint32_t r = (u + 0x7fffu + ((u >> 16) & 1u)) >> 16;
  return (uint16_t)r;
}

// ---------------- dtype detection -------------------------------------------
__global__ __launch_bounds__(256) void detect_kernel(const uint16_t* __restrict__ x,
                                                     int* __restrict__ flag){
  __shared__ int cnt;
  if (threadIdx.x == 0) cnt = 0;
  __syncthreads();
  int good = 0;
  for (int i = threadIdx.x; i < 512; i += 256){
    uint16_t v = x[i];
    int e = (v >> 7) & 0xFF;
    good += (e >= 115 && e <= 131) ? 1 : 0;
  }
  atomicAdd(&cnt, good);
  __syncthreads();
  if (threadIdx.x == 0) *flag = (cnt >= 400) ? 1 : 0;
}

// ---------------- convert all float inputs into a bf16 arena ----------------
struct Ptrs { const void* p[21]; };

__constant__ int c_off[22] = {
  0, 5640192, 6033408, 6033472, 6033728, 6033984, 6427200, 6427264, 6427520,
  6427776, 6820992, 6821056, 6821312, 6821568, 7214784, 7214848, 7215104,
  7215360, 7543040, 7543296, 7543552, 7543808};

__global__ __launch_bounds__(256) void convert_kernel(Ptrs ptrs,
        const int* __restrict__ flag, uint16_t* __restrict__ arena){
  long base = ((long)blockIdx.x * 256 + threadIdx.x) * 8;
  if (base >= 7543808L) return;
  int seg = 0;
  while (c_off[seg + 1] <= base) seg++;
  long loc = base - c_off[seg];
  if (*flag){
    *(s8v*)(arena + base) = *(const s8v*)((const uint16_t*)ptrs.p[seg] + loc);
  } else {
    const float* s = (const float*)ptrs.p[seg] + loc;
    f4v a = *(const f4v*)s;
    f4v b = *(const f4v*)(s + 4);
    s8v o;
    #pragma unroll
    for (int u = 0; u < 4; u++){ o[u] = (short)f2b(a[u]); o[4+u] = (short)f2b(b[u]); }
    *(s8v*)(arena + base) = o;
  }
}

// ---------------- prep ---------------------------------------------------------
__global__ __launch_bounds__(256) void prep_kernel(const uint16_t* __restrict__ x,
                     uint16_t* __restrict__ xc0, uint16_t* __restrict__ y){
  long i = (long)blockIdx.x * 256 + threadIdx.x;
  const long n1 = (long)F_FRAMES * JC * CH;
  const long n2 = (long)MREAL * CH;
  const long n3 = (long)(M2 - MREAL) * K2;
  if (i < n1){
    long f = i / (JC*CH); long r = i % (JC*CH);
    int j = (int)(r >> 8); int c = (int)(r & 255);
    uint16_t v = 0;
    if (j < 17) v = x[(f*17 + j)*CH + c];
    xc0[i] = v;
  } else if (i < n1 + n2){
    long i2 = i - n1;
    long row = i2 >> 8; int c = (int)(i2 & 255);
    y[row*K2 + c] = x[i2];
  } else if (i < n1 + n2 + n3){
    long i3 = i - n1 - n2;
    long row = MREAL + i3 / K2; int c = (int)(i3 % K2);
    y[row*K2 + c] = 0;
  }
}

// ---------------- build per-src edge lists (once per call) -------------------
__global__ __launch_bounds__(64) void build_elist(const int* __restrict__ eskel,
        const int* __restrict__ ecay, int* __restrict__ out){
  int t = threadIdx.x;
  int g = t >> 5, j = t & 31;
  if (j < 24){
    const int* ed = g ? ecay : eskel;
    int E = g ? 120 : 49;
    int c = 0;
    for (int e = 0; e < E; e++)
      if (ed[e] == j){ out[48 + (g*24 + j)*8 + c] = e; c++; }
    out[g*24 + j] = c;
  }
}

// ---------------- wv_copy: gather v-rows of all 4 W's into [512][256] --------
struct WPtrs { const uint16_t* w[4]; };
__global__ __launch_bounds__(256) void wv_copy(WPtrs wp, uint16_t* __restrict__ wv){
  int g = blockIdx.x * 256 + threadIdx.x;
  int L = g >> 14;
  int loc = g & 16383;
  int row = loc >> 5;
  int col = (loc & 31) * 8;
  int wrow = (row >> 6) * 192 + 128 + (row & 63);
  *(s8v*)(wv + ((long)L*512 + row)*256 + col) =
      *(const s8v*)(wp.w[L] + (long)wrow*256 + col);
}

// ---------------- GEMM: XCD swizzle + T2 chunk-XOR LDS swizzle ----------------
template<int OUT_F32>
__global__ __launch_bounds__(256) void gemm_bt(const uint16_t* __restrict__ A,
        const uint16_t* __restrict__ B, void* __restrict__ Cv,
        int M, int N, int K, int nbn){
  __shared__ uint16_t As[128*64];
  __shared__ uint16_t Bs[128*64];
  int t = threadIdx.x;
  int lane = t & 63, w = t >> 6;
  int wr = (w >> 1) * 64, wc = (w & 1) * 64;

  int total = gridDim.x;
  int q = total >> 3, r = total & 7;
  int orig = blockIdx.x;
  int xcd = orig & 7, loc = orig >> 3;
  int wgid = (xcd < r ? xcd*(q+1) : r*(q+1) + (xcd-r)*q) + loc;
  long bm = (long)(wgid / nbn) * 128;
  long bn = (long)(wgid % nbn) * 128;

  f4v acc[4][4];
  #pragma unroll
  for (int i=0;i<4;i++){
    #pragma unroll
    for (int jq=0;jq<4;jq++) acc[i][jq] = (f4v){0.f,0.f,0.f,0.f};
  }
  const int nk = K >> 6;
  for (int kt = 0; kt < nk; ++kt){
    const uint16_t* Ag = A + bm * K + kt*64;
    const uint16_t* Bg = B + bn * K + kt*64;
    #pragma unroll
    for (int i=0;i<4;i++){
      int flat = i*256 + t;
      int row = flat >> 3, col = ((flat ^ row) & 7) << 3;   // inverse-swizzled src
      __builtin_amdgcn_global_load_lds(
        (const GLOBAL_AS void*)(Ag + (long)row*K + col),
        (LDS_AS void*)(As + flat*8), 16, 0, 0);
    }
    #pragma unroll
    for (int i=0;i<4;i++){
      int flat = i*256 + t;
      int row = flat >> 3, col = ((flat ^ row) & 7) << 3;
      __builtin_amdgcn_global_load_lds(
        (const GLOBAL_AS void*)(Bg + (long)row*K + col),
        (LDS_AS void*)(Bs + flat*8), 16, 0, 0);
    }
    __syncthreads();
    #pragma unroll
    for (int kk=0; kk<2; ++kk){
      s8v af[4], bfr[4];
      int ch = kk*4 + (lane>>4);
      #pragma unroll
      for (int mi=0;mi<4;mi++){
        int row = wr + mi*16 + (lane&15);
        af[mi] = *(const s8v*)(As + row*64 + ((ch ^ (row&7))<<3));
      }
      #pragma unroll
      for (int ni=0;ni<4;ni++){
        int row = wc + ni*16 + (lane&15);
        bfr[ni] = *(const s8v*)(Bs + row*64 + ((ch ^ (row&7))<<3));
      }
      #pragma unroll
      for (int mi=0;mi<4;mi++){
        #pragma unroll
        for (int ni=0;ni<4;ni++)
          acc[mi][ni] = __builtin_amdgcn_mfma_f32_16x16x32_bf16(af[mi], bfr[ni], acc[mi][ni], 0,0,0);
      }
    }
    __syncthreads();
  }
  #pragma unroll
  for (int mi=0;mi<4;mi++){
    #pragma unroll
    for (int ni=0;ni<4;ni++){
      long col = bn + wc + ni*16 + (lane & 15);
      #pragma unroll
      for (int r2=0;r2<4;r2++){
        long row = bm + wr + mi*16 + (lane>>4)*4 + r2;
        if (OUT_F32) ((float*)Cv)[row*N + col] = acc[mi][ni][r2];
        else ((uint16_t*)Cv)[row*N + col] = f2b(acc[mi][ni][r2]);
      }
    }
  }
}

// ---------------- qk GEMM + fused logits, 512 threads = 8 waves --------------
// M=96 (4 frames), N=128 (head h q|k), K=256. Waves: wr in {0,1} x wc in {0..3}.
__global__ __launch_bounds__(512) void qk_logit(
    const uint16_t* __restrict__ xc_in, const uint16_t* __restrict__ W,
    const uint16_t* __restrict__ aw, const int* __restrict__ edges,
    float* __restrict__ sexg, int E)
{
  __shared__ uint16_t AB[14336];    // As[0:6144] Bs[6144:14336]; qs reuses [0:12288]
  __shared__ float awf[64];
  __shared__ int esrc[EMAX], edst[EMAX];

  int t = threadIdx.x;
  int lane = t & 63, w = t >> 6;
  int wr = w >> 2, wc = w & 3;

  int orig = blockIdx.x;                 // 2592 = 8*324
  int wgid = (orig & 7) * 324 + (orig >> 3);
  int mp = wgid >> 3;                    // M panel (4 frames)
  int h  = wgid & 7;                     // head

  if (t < E){ esrc[t] = edges[t]; edst[t] = edges[E+t]; }
  if (t >= 128 && t < 192) awf[t-128] = b2f(aw[t-128]);

  uint16_t* As = AB;
  uint16_t* Bs = AB + 6144;
  const uint16_t* Ag0 = xc_in + (long)mp*96*256;
  const uint16_t* Bg0 = W + (long)h*192*256;

  f4v acc[3][2];
  #pragma unroll
  for (int i=0;i<3;i++){
    acc[i][0] = (f4v){0.f,0.f,0.f,0.f};
    acc[i][1] = (f4v){0.f,0.f,0.f,0.f};
  }

  for (int kt = 0; kt < 4; ++kt){
    {
      int g = t;                          // A granules 0..767 (512 + 256)
      int row = g >> 3, col = ((g ^ row) & 7) << 3;
      __builtin_amdgcn_global_load_lds(
        (const GLOBAL_AS void*)(Ag0 + (long)row*256 + kt*64 + col),
        (LDS_AS void*)(As + g*8), 16, 0, 0);
      if (t < 256){
        g = 512 + t;
        row = g >> 3; col = ((g ^ row) & 7) << 3;
        __builtin_amdgcn_global_load_lds(
          (const GLOBAL_AS void*)(Ag0 + (long)row*256 + kt*64 + col),
          (LDS_AS void*)(As + g*8), 16, 0, 0);
      }
    }
    #pragma unroll
    for (int i=0;i<2;i++){
      int g = i*512 + t;                 // B granules 0..1023
      int row = g >> 3, col = ((g ^ row) & 7) << 3;
      __builtin_amdgcn_global_load_lds(
        (const GLOBAL_AS void*)(Bg0 + (long)row*256 + kt*64 + col),
        (LDS_AS void*)(Bs + g*8), 16, 0, 0);
    }
    __syncthreads();
    #pragma unroll
    for (int kk=0; kk<2; ++kk){
      s8v af[3], bfr[2];
      int ch = kk*4 + (lane>>4);
      #pragma unroll
      for (int mi=0;mi<3;mi++){
        int row = wr*48 + mi*16 + (lane&15);
        af[mi] = *(const s8v*)(As + row*64 + ((ch ^ (row&7))<<3));
      }
      #pragma unroll
      for (int ni=0;ni<2;ni++){
        int row = wc*32 + ni*16 + (lane&15);
        bfr[ni] = *(const s8v*)(Bs + row*64 + ((ch ^ (row&7))<<3));
      }
      #pragma unroll
      for (int mi=0;mi<3;mi++){
        #pragma unroll
        for (int ni=0;ni<2;ni++)
          acc[mi][ni] = __builtin_amdgcn_mfma_f32_16x16x32_bf16(af[mi], bfr[ni], acc[mi][ni], 0,0,0);
      }
    }
    __syncthreads();
  }

  // C -> LDS qs[96][128], 16B-chunk XOR swizzle by row
  uint16_t* qs = AB;
  #pragma unroll
  for (int mi=0;mi<3;mi++){
    #pragma unroll
    for (int ni=0;ni<2;ni++){
      int col = wc*32 + ni*16 + (lane & 15);
      int ch = col >> 3;
      #pragma unroll
      for (int r2=0;r2<4;r2++){
        int row = wr*48 + mi*16 + (lane>>4)*4 + r2;
        int pch = (ch & 8) | ((ch ^ row) & 7);
        qs[row*128 + pch*8 + (col & 7)] = f2b(acc[mi][ni][r2]);
      }
    }
  }
  __syncthreads();

  // logits: items = 4 frames x E edges, 8 lanes per item
  float areg[8], aregc[8];
  {
    int ln = t & 7;
    #pragma unroll
    for (int u=0;u<8;u++){
      areg[u] = awf[ln*8 + u];
      aregc[u] = areg[u] * 0.69314718056f;
    }
  }
  const int items = 4*E;
  for (int base = 0; base < items*8; base += 512){
    int slot = base + t;
    int item = slot >> 3;
    int ln = slot & 7;
    float s = 0.f;
    int fl = 0, e = 0;
    if (item < items){
      fl = item / E; e = item - fl*E;
      int rs = fl*24 + esrc[e];
      int rd = fl*24 + edst[e];
      const uint16_t* qp = qs + rs*128 + ((ln ^ rs) & 7)*8;
      const uint16_t* kp = qs + rd*128 + (8 | ((ln ^ rd) & 7))*8;
      s8v qv = *(const s8v*)qp;
      s8v kv = *(const s8v*)kp;
      #pragma unroll
      for (int u=0;u<8;u++){
        float xv = b2f((uint16_t)qv[u]) + b2f((uint16_t)kv[u]);
        float e2 = __builtin_amdgcn_exp2f(fabsf(xv) * -1.44269504f);
        float lg = __builtin_amdgcn_logf(1.f + e2);
        s = fmaxf(xv, 0.f) * areg[u] + s;
        s = lg * aregc[u] + s;
      }
    }
    s += __shfl_xor(s, 1, 64);
    s += __shfl_xor(s, 2, 64);
    s += __shfl_xor(s, 4, 64);
    if (item < items && ln == 0)
      sexg[((long)mp*4 + fl)*(E*NH) + e*NH + h] = s;
  }
}

// ---------------- gat: softmax + aggregate + residual + LN -------------------
__global__ __launch_bounds__(256) void gat_kernel(
    const uint16_t* __restrict__ vg, const uint16_t* __restrict__ xc,
    const int* __restrict__ edges, const float* __restrict__ sexg,
    const int* __restrict__ elg,
    const uint16_t* __restrict__ gw, const uint16_t* __restrict__ bw,
    uint16_t* __restrict__ xc_out, uint16_t* __restrict__ y,
    int E, int ycol, int graph)
{
  __shared__ uint16_t v2s[JC*NH*32];   // 12288 B, swizzled
  __shared__ float sexs[EMAX*NH];
  __shared__ float smax[NH];
  __shared__ int edst[EMAX];
  __shared__ uint16_t glb[2*CH];

  int f = blockIdx.x;
  int t = threadIdx.x;
  const uint16_t* vf = vg + (long)f * JC * 512;
  const int EN = E * NH;

  #pragma unroll
  for (int i=0;i<3;i++){
    int g = i*256 + t;
    int r = g >> 2, cs = g & 3;
    int c = cs ^ ((r >> 1) & 3);
    int j = r >> 3, h = r & 7;
    const uint16_t* s2 = vf + j*512 + h*64 + 32 + c*8;
    __builtin_amdgcn_global_load_lds((const GLOBAL_AS void*)s2,
        (LDS_AS void*)(v2s + g*8), 16, 0, 0);
  }
  if (t < E) edst[t] = edges[E + t];
  if (t < (EN >> 2)) ((f4v*)sexs)[t] = ((const f4v*)(sexg + (long)f*EN))[t];
  glb[t] = gw[t]; glb[256 + t] = bw[t];
  __syncthreads();

  if (t < 64){
    int h = t & 7;
    float m = -3.4e38f;
    for (int e = t >> 3; e < E; e += 8) m = fmaxf(m, sexs[e*8 + h]);
    m = fmaxf(m, __shfl_xor(m, 8, 64));
    m = fmaxf(m, __shfl_xor(m, 16, 64));
    m = fmaxf(m, __shfl_xor(m, 32, 64));
    if (t < 8) smax[t] = m;
  }
  __syncthreads();

  if (t < JC*NH){
    int j = t >> 3, h = t & 7;
    int deg = elg[graph*24 + j];
    const int* lst = elg + 48 + (graph*24 + j)*8;
    float mh = smax[h];
    float ex[8];
    float sig = 1e-10f;
    int el[8];
    #pragma unroll
    for (int i=0;i<8;i++){
      float v = 0.f; int e = 0;
      if (i < deg){ e = lst[i]; v = __builtin_amdgcn_exp2f((sexs[e*8+h] - mh) * 1.44269504f); }
      el[i] = e; ex[i] = v; sig += v;
    }
    float inv = 1.f / sig;
    float acc[32];
    #pragma unroll
    for (int d=0;d<32;d++) acc[d] = 0.f;
    #pragma unroll
    for (int i=0;i<8;i++){
      if (i < deg){
        float wgt = ex[i] * inv;
        int r = edst[el[i]]*8 + h;
        int sw = (r >> 1) & 3;
        #pragma unroll
        for (int c=0;c<4;c++){
          s8v v = *(const s8v*)(v2s + r*32 + (c ^ sw)*8);
          #pragma unroll
          for (int u=0;u<8;u++) acc[c*8+u] += wgt * b2f((uint16_t)v[u]);
        }
      }
    }

    const uint16_t* v1p = vf + j*512 + h*64;
    const uint16_t* xp = xc + (long)f*JC*CH + t*32;
    float pre[32]; float sum = 0.f, sq = 0.f;
    #pragma unroll
    for (int c=0;c<4;c++){
      s8v v1 = *(const s8v*)(v1p + c*8);
      s8v xv = *(const s8v*)(xp + c*8);
      #pragma unroll
      for (int u=0;u<8;u++){
        float p = b2f((uint16_t)xv[u]) + 0.2f*b2f((uint16_t)v1[u]) + 0.8f*acc[c*8+u];
        pre[c*8+u] = p; sum += p; sq += p*p;
      }
    }
    #pragma unroll
    for (int m=1;m<8;m<<=1){ sum += __shfl_xor(sum, m, 64); sq += __shfl_xor(sq, m, 64); }
    float mean = sum * (1.f/256.f);
    float var = sq * (1.f/256.f) - mean*mean;
    float rstd = rsqrtf(var + 1e-5f);
    uint16_t* xo = xc_out + (long)f*JC*CH + t*32;
    uint16_t* yo = (j < 17) ? (y + (long)(f*17 + j)*K2 + ycol + h*32) : (uint16_t*)0;
    #pragma unroll
    for (int d0=0; d0<32; d0+=8){
      s8v ov;
      #pragma unroll
      for (int u=0;u<8;u++){
        int c = h*32 + d0 + u;
        float val = (pre[d0+u]-mean)*rstd*b2f(glb[c]) + b2f(glb[256+c]);
        ov[u] = (short)f2b(val);
      }
      *(s8v*)(xo + d0) = ov;
      if (yo) *(s8v*)(yo + d0) = ov;
    }
  }
}

// ---------------- final bias + LN --------------------------------------------
__global__ __launch_bounds__(256) void final_ln(const float* __restrict__ pre,
    const uint16_t* __restrict__ pb, const uint16_t* __restrict__ gp,
    const uint16_t* __restrict__ bp, const int* __restrict__ flag,
    void* __restrict__ out){
  int row = blockIdx.x*4 + (threadIdx.x>>6);
  int lane = threadIdx.x & 63;
  const float* p = pre + (long)row*CH + lane*4;
  f4v pv = *(const f4v*)p;
  float v[4]; float sum = 0.f, sq = 0.f;
  #pragma unroll
  for (int i=0;i<4;i++){ int c = lane*4+i; v[i] = pv[i] + b2f(pb[c]); sum += v[i]; sq += v[i]*v[i]; }
  #pragma unroll
  for (int m=1;m<64;m<<=1){ sum += __shfl_xor(sum, m, 64); sq += __shfl_xor(sq, m, 64); }
  float mean = sum * (1.f/256.f);
  float var = sq * (1.f/256.f) - mean*mean;
  float rstd = rsqrtf(var + 1e-5f);
  float o[4];
  #pragma unroll
  for (int i=0;i<4;i++){
    int c = lane*4+i;
    o[i] = (v[i]-mean)*rstd*b2f(gp[c]) + b2f(bp[c]);
  }
  if (*flag){
    s4v ov;
    #pragma unroll
    for (int i=0;i<4;i++) ov[i] = (short)f2b(o[i]);
    *(s4v*)((uint16_t*)out + (long)row*CH + lane*4) = ov;
  } else {
    f4v ov;
    #pragma unroll
    for (int i=0;i<4;i++) ov[i] = o[i];
    *(f4v*)((float*)out + (long)row*CH + lane*4) = ov;
  }
}

// ---------------- launch ------------------------------------------------------
extern "C" void kernel_launch(void* const* d_in, const int* in_sizes, int n_in,
                              void* d_out, int out_size, void* d_ws, size_t ws_size,
                              hipStream_t stream){
  const int* eskel = (const int*)d_in[21];
  const int* ecay  = (const int*)d_in[22];

  char* ws = (char*)d_ws;
  const size_t QKV_B  = (size_t)M1 * N1 * 2;
  const size_t XC_B   = (size_t)M1 * CH * 2;
  const size_t Y_B    = (size_t)M2 * K2 * 2;
  const size_t ARENA_OFF = QKV_B + 2*XC_B + Y_B;
  const size_t ARENA_B = 7543808L * 2;
  uint16_t* vout = (uint16_t*)ws;
  float*    pre  = (float*)ws;
  uint16_t* xcA = (uint16_t*)(ws + QKV_B);
  uint16_t* xcB = (uint16_t*)(ws + QKV_B + XC_B);
  uint16_t* y   = (uint16_t*)(ws + QKV_B + 2*XC_B);
  uint16_t* arena = (uint16_t*)(ws + ARENA_OFF);
  int*      flag  = (int*)(ws + ARENA_OFF + ARENA_B);
  int*      elg   = flag + 16;
  uint16_t* wv    = (uint16_t*)(ws + ARENA_OFF + ARENA_B + 4096);
  float*    sexg  = (float*)arena;

  const uint16_t* x_bf = arena;
  const uint16_t* wq[4] = {arena + 5640192, arena + 6033984, arena + 6427776, arena + 6821568};
  const uint16_t* aw[4] = {arena + 6033408, arena + 6427200, arena + 6820992, arena + 7214784};
  const uint16_t* gg[4] = {arena + 6033472, arena + 6427264, arena + 6821056, arena + 7214848};
  const uint16_t* bb[4] = {arena + 6033728, arena + 6427520, arena + 6821312, arena + 7215104};
  const uint16_t* pw = arena + 7215360;
  const uint16_t* pb = arena + 7543040;
  const uint16_t* gp = arena + 7543296;
  const uint16_t* bp = arena + 7543552;

  detect_kernel<<<1, 256, 0, stream>>>((const uint16_t*)d_in[0], flag);

  Ptrs ptrs;
  for (int i = 0; i < 21; i++) ptrs.p[i] = d_in[i];
  convert_kernel<<<3684, 256, 0, stream>>>(ptrs, flag, arena);

  prep_kernel<<<53696, 256, 0, stream>>>(x_bf, xcA, y);
  build_elist<<<1, 64, 0, stream>>>(eskel, ecay, elg);

  WPtrs wp = {{wq[0], wq[1], wq[2], wq[3]}};
  wv_copy<<<256, 256, 0, stream>>>(wp, wv);

  uint16_t* xcs[2] = {xcA, xcB};
  for (int L = 0; L < 4; ++L){
    const int* ed = (L & 1) ? ecay : eskel;
    int E = (L & 1) ? 120 : 49;
    qk_logit<<<2592, 512, 0, stream>>>(xcs[L & 1], wq[L], aw[L], ed, sexg, E);
    gemm_bt<0><<<972, 256, 0, stream>>>(xcs[L & 1], wv + (long)L*512*256, vout,
                                        M1, 512, K1, 4);
    gat_kernel<<<F_FRAMES, 256, 0, stream>>>(vout, xcs[L & 1], ed, sexg, elg,
                                             gg[L], bb[L],
                                             xcs[(L + 1) & 1], y, E, (L + 1) * 256, L & 1);
  }
  gemm_bt<1><<<346, 256, 0, stream>>>(y, pw, pre, M2, N2, K2, 2);
  final_ln<<<5508, 256, 0, stream>>>(pre, pb, gp, bp, flag, d_out);
}

// Round 10
// 424.568 us; speedup vs baseline: 2.2179x; 1.1294x over previous
//
#include <hip/hip_runtime.h>
#include <stdint.h>

#define F_FRAMES 1296
#define JC 24
#define CH 256
#define NH 8
#define EMAX 120
#define M1 31104
#define N1 1536
#define K1 256
#define M2 22144
#define MREAL 22032
#define K2 1280
#define N2 256

typedef __attribute__((ext_vector_type(8))) short s8v;
typedef __attribute__((ext_vector_type(4))) short s4v;
typedef __attribute__((ext_vector_type(4))) float f4v;

#define GLOBAL_AS __attribute__((address_space(1)))
#define LDS_AS __attribute__((address_space(3)))

__device__ __forceinline__ float b2f(uint16_t u){
  union { float f; uint32_t u; } v; v.u = ((uint32_t)u) << 16; return v.f;
}
__device__ __forceinline__ uint16_t f2b(float f){
  union { float f; uint32_t u; } v; v.f = f;
  uint32_t u = v.u;
  uint32_t r = (u + 0x7fffu + ((u >> 16) & 1u)) >> 16;
  return (uint16_t)r;
}

// ---------------- dtype detection -------------------------------------------
__global__ __launch_bounds__(256) void detect_kernel(const uint16_t* __restrict__ x,
                                                     int* __restrict__ flag){
  __shared__ int cnt;
  if (threadIdx.x == 0) cnt = 0;
  __syncthreads();
  int good = 0;
  for (int i = threadIdx.x; i < 512; i += 256){
    uint16_t v = x[i];
    int e = (v >> 7) & 0xFF;
    good += (e >= 115 && e <= 131) ? 1 : 0;
  }
  atomicAdd(&cnt, good);
  __syncthreads();
  if (threadIdx.x == 0) *flag = (cnt >= 400) ? 1 : 0;
}

// ---------------- convert all float inputs into a bf16 arena ----------------
struct Ptrs { const void* p[21]; };

__constant__ int c_off[22] = {
  0, 5640192, 6033408, 6033472, 6033728, 6033984, 6427200, 6427264, 6427520,
  6427776, 6820992, 6821056, 6821312, 6821568, 7214784, 7214848, 7215104,
  7215360, 7543040, 7543296, 7543552, 7543808};

__global__ __launch_bounds__(256) void convert_kernel(Ptrs ptrs,
        const int* __restrict__ flag, uint16_t* __restrict__ arena){
  long base = ((long)blockIdx.x * 256 + threadIdx.x) * 8;
  if (base >= 7543808L) return;
  int seg = 0;
  while (c_off[seg + 1] <= base) seg++;
  long loc = base - c_off[seg];
  if (*flag){
    *(s8v*)(arena + base) = *(const s8v*)((const uint16_t*)ptrs.p[seg] + loc);
  } else {
    const float* s = (const float*)ptrs.p[seg] + loc;
    f4v a = *(const f4v*)s;
    f4v b = *(const f4v*)(s + 4);
    s8v o;
    #pragma unroll
    for (int u = 0; u < 4; u++){ o[u] = (short)f2b(a[u]); o[4+u] = (short)f2b(b[u]); }
    *(s8v*)(arena + base) = o;
  }
}

// ---------------- prep ---------------------------------------------------------
__global__ __launch_bounds__(256) void prep_kernel(const uint16_t* __restrict__ x,
                     uint16_t* __restrict__ xc0, uint16_t* __restrict__ y){
  long i = (long)blockIdx.x * 256 + threadIdx.x;
  const long n1 = (long)F_FRAMES * JC * CH;
  const long n2 = (long)MREAL * CH;
  const long n3 = (long)(M2 - MREAL) * K2;
  if (i < n1){
    long f = i / (JC*CH); long r = i % (JC*CH);
    int j = (int)(r >> 8); int c = (int)(r & 255);
    uint16_t v = 0;
    if (j < 17) v = x[(f*17 + j)*CH + c];
    xc0[i] = v;
  } else if (i < n1 + n2){
    long i2 = i - n1;
    long row = i2 >> 8; int c = (int)(i2 & 255);
    y[row*K2 + c] = x[i2];
  } else if (i < n1 + n2 + n3){
    long i3 = i - n1 - n2;
    long row = MREAL + i3 / K2; int c = (int)(i3 % K2);
    y[row*K2 + c] = 0;
  }
}

// ---------------- build per-src edge lists (once per call) -------------------
__global__ __launch_bounds__(64) void build_elist(const int* __restrict__ eskel,
        const int* __restrict__ ecay, int* __restrict__ out){
  int t = threadIdx.x;
  int g = t >> 5, j = t & 31;
  if (j < 24){
    const int* ed = g ? ecay : eskel;
    int E = g ? 120 : 49;
    int c = 0;
    for (int e = 0; e < E; e++)
      if (ed[e] == j){ out[48 + (g*24 + j)*8 + c] = e; c++; }
    out[g*24 + j] = c;
  }
}

// ---------------- wv_copy: gather v-rows of all 4 W's into [512][256] --------
struct WPtrs { const uint16_t* w[4]; };
__global__ __launch_bounds__(256) void wv_copy(WPtrs wp, uint16_t* __restrict__ wv){
  int g = blockIdx.x * 256 + threadIdx.x;
  int L = g >> 14;
  int loc = g & 16383;
  int row = loc >> 5;
  int col = (loc & 31) * 8;
  int wrow = (row >> 6) * 192 + 128 + (row & 63);
  *(s8v*)(wv + ((long)L*512 + row)*256 + col) =
      *(const s8v*)(wp.w[L] + (long)wrow*256 + col);
}

// ---------------- GEMM: XCD swizzle + T2 chunk-XOR LDS swizzle ----------------
template<int OUT_F32>
__global__ __launch_bounds__(256) void gemm_bt(const uint16_t* __restrict__ A,
        const uint16_t* __restrict__ B, void* __restrict__ Cv,
        int M, int N, int K, int nbn){
  __shared__ uint16_t As[128*64];
  __shared__ uint16_t Bs[128*64];
  int t = threadIdx.x;
  int lane = t & 63, w = t >> 6;
  int wr = (w >> 1) * 64, wc = (w & 1) * 64;

  int total = gridDim.x;
  int q = total >> 3, r = total & 7;
  int orig = blockIdx.x;
  int xcd = orig & 7, loc = orig >> 3;
  int wgid = (xcd < r ? xcd*(q+1) : r*(q+1) + (xcd-r)*q) + loc;
  long bm = (long)(wgid / nbn) * 128;
  long bn = (long)(wgid % nbn) * 128;

  f4v acc[4][4];
  #pragma unroll
  for (int i=0;i<4;i++){
    #pragma unroll
    for (int jq=0;jq<4;jq++) acc[i][jq] = (f4v){0.f,0.f,0.f,0.f};
  }
  const int nk = K >> 6;
  for (int kt = 0; kt < nk; ++kt){
    const uint16_t* Ag = A + bm * K + kt*64;
    const uint16_t* Bg = B + bn * K + kt*64;
    #pragma unroll
    for (int i=0;i<4;i++){
      int flat = i*256 + t;
      int row = flat >> 3, col = ((flat ^ row) & 7) << 3;
      __builtin_amdgcn_global_load_lds(
        (const GLOBAL_AS void*)(Ag + (long)row*K + col),
        (LDS_AS void*)(As + flat*8), 16, 0, 0);
    }
    #pragma unroll
    for (int i=0;i<4;i++){
      int flat = i*256 + t;
      int row = flat >> 3, col = ((flat ^ row) & 7) << 3;
      __builtin_amdgcn_global_load_lds(
        (const GLOBAL_AS void*)(Bg + (long)row*K + col),
        (LDS_AS void*)(Bs + flat*8), 16, 0, 0);
    }
    __syncthreads();
    #pragma unroll
    for (int kk=0; kk<2; ++kk){
      s8v af[4], bfr[4];
      int ch = kk*4 + (lane>>4);
      #pragma unroll
      for (int mi=0;mi<4;mi++){
        int row = wr + mi*16 + (lane&15);
        af[mi] = *(const s8v*)(As + row*64 + ((ch ^ (row&7))<<3));
      }
      #pragma unroll
      for (int ni=0;ni<4;ni++){
        int row = wc + ni*16 + (lane&15);
        bfr[ni] = *(const s8v*)(Bs + row*64 + ((ch ^ (row&7))<<3));
      }
      #pragma unroll
      for (int mi=0;mi<4;mi++){
        #pragma unroll
        for (int ni=0;ni<4;ni++)
          acc[mi][ni] = __builtin_amdgcn_mfma_f32_16x16x32_bf16(af[mi], bfr[ni], acc[mi][ni], 0,0,0);
      }
    }
    __syncthreads();
  }
  #pragma unroll
  for (int mi=0;mi<4;mi++){
    #pragma unroll
    for (int ni=0;ni<4;ni++){
      long col = bn + wc + ni*16 + (lane & 15);
      #pragma unroll
      for (int r2=0;r2<4;r2++){
        long row = bm + wr + mi*16 + (lane>>4)*4 + r2;
        if (OUT_F32) ((float*)Cv)[row*N + col] = acc[mi][ni][r2];
        else ((uint16_t*)Cv)[row*N + col] = f2b(acc[mi][ni][r2]);
      }
    }
  }
}

// ---------------- qk GEMM + fused logits, 512 threads, E compile-time ---------
template<int E>
__global__ __launch_bounds__(512) void qk_logit(
    const uint16_t* __restrict__ xc_in, const uint16_t* __restrict__ W,
    const uint16_t* __restrict__ aw, const int* __restrict__ edges,
    float* __restrict__ sexg)
{
  __shared__ uint16_t AB[14336];
  __shared__ float awf[64];
  __shared__ int esrc[EMAX], edst[EMAX];

  int t = threadIdx.x;
  int lane = t & 63, w = t >> 6;
  int wr = w >> 2, wc = w & 3;

  int orig = blockIdx.x;                 // 2592 = 8*324
  int wgid = (orig & 7) * 324 + (orig >> 3);
  int mp = wgid >> 3;
  int h  = wgid & 7;

  if (t < E){ esrc[t] = edges[t]; edst[t] = edges[E+t]; }
  if (t >= 128 && t < 192) awf[t-128] = b2f(aw[t-128]);

  uint16_t* As = AB;
  uint16_t* Bs = AB + 6144;
  const uint16_t* Ag0 = xc_in + (long)mp*96*256;
  const uint16_t* Bg0 = W + (long)h*192*256;

  f4v acc[3][2];
  #pragma unroll
  for (int i=0;i<3;i++){
    acc[i][0] = (f4v){0.f,0.f,0.f,0.f};
    acc[i][1] = (f4v){0.f,0.f,0.f,0.f};
  }

  for (int kt = 0; kt < 4; ++kt){
    {
      int g = t;
      int row = g >> 3, col = ((g ^ row) & 7) << 3;
      __builtin_amdgcn_global_load_lds(
        (const GLOBAL_AS void*)(Ag0 + (long)row*256 + kt*64 + col),
        (LDS_AS void*)(As + g*8), 16, 0, 0);
      if (t < 256){
        g = 512 + t;
        row = g >> 3; col = ((g ^ row) & 7) << 3;
        __builtin_amdgcn_global_load_lds(
          (const GLOBAL_AS void*)(Ag0 + (long)row*256 + kt*64 + col),
          (LDS_AS void*)(As + g*8), 16, 0, 0);
      }
    }
    #pragma unroll
    for (int i=0;i<2;i++){
      int g = i*512 + t;
      int row = g >> 3, col = ((g ^ row) & 7) << 3;
      __builtin_amdgcn_global_load_lds(
        (const GLOBAL_AS void*)(Bg0 + (long)row*256 + kt*64 + col),
        (LDS_AS void*)(Bs + g*8), 16, 0, 0);
    }
    __syncthreads();
    #pragma unroll
    for (int kk=0; kk<2; ++kk){
      s8v af[3], bfr[2];
      int ch = kk*4 + (lane>>4);
      #pragma unroll
      for (int mi=0;mi<3;mi++){
        int row = wr*48 + mi*16 + (lane&15);
        af[mi] = *(const s8v*)(As + row*64 + ((ch ^ (row&7))<<3));
      }
      #pragma unroll
      for (int ni=0;ni<2;ni++){
        int row = wc*32 + ni*16 + (lane&15);
        bfr[ni] = *(const s8v*)(Bs + row*64 + ((ch ^ (row&7))<<3));
      }
      #pragma unroll
      for (int mi=0;mi<3;mi++){
        #pragma unroll
        for (int ni=0;ni<2;ni++)
          acc[mi][ni] = __builtin_amdgcn_mfma_f32_16x16x32_bf16(af[mi], bfr[ni], acc[mi][ni], 0,0,0);
      }
    }
    __syncthreads();
  }

  uint16_t* qs = AB;
  #pragma unroll
  for (int mi=0;mi<3;mi++){
    #pragma unroll
    for (int ni=0;ni<2;ni++){
      int col = wc*32 + ni*16 + (lane & 15);
      int ch = col >> 3;
      #pragma unroll
      for (int r2=0;r2<4;r2++){
        int row = wr*48 + mi*16 + (lane>>4)*4 + r2;
        int pch = (ch & 8) | ((ch ^ row) & 7);
        qs[row*128 + pch*8 + (col & 7)] = f2b(acc[mi][ni][r2]);
      }
    }
  }
  __syncthreads();

  float areg[8], aregc[8];
  {
    int ln = t & 7;
    #pragma unroll
    for (int u=0;u<8;u++){
      areg[u] = awf[ln*8 + u];
      aregc[u] = areg[u] * 0.69314718056f;
    }
  }
  const int items = 4*E;                 // compile-time
  for (int base = 0; base < items*8; base += 512){
    int slot = base + t;
    int item = slot >> 3;
    int ln = slot & 7;
    float s = 0.f;
    int fl = 0, e = 0;
    if (item < items){
      fl = item / E;                     // magic-mul (E constant)
      e = item - fl*E;
      int rs = fl*24 + esrc[e];
      int rd = fl*24 + edst[e];
      const uint16_t* qp = qs + rs*128 + ((ln ^ rs) & 7)*8;
      const uint16_t* kp = qs + rd*128 + (8 | ((ln ^ rd) & 7))*8;
      s8v qv = *(const s8v*)qp;
      s8v kv = *(const s8v*)kp;
      #pragma unroll
      for (int u=0;u<8;u++){
        float xv = b2f((uint16_t)qv[u]) + b2f((uint16_t)kv[u]);
        float e2 = __builtin_amdgcn_exp2f(fabsf(xv) * -1.44269504f);
        float lg = __builtin_amdgcn_logf(1.f + e2);
        s = fmaxf(xv, 0.f) * areg[u] + s;
        s = lg * aregc[u] + s;
      }
    }
    s += __shfl_xor(s, 1, 64);
    s += __shfl_xor(s, 2, 64);
    s += __shfl_xor(s, 4, 64);
    if (item < items && ln == 0)
      sexg[((long)mp*4 + fl)*(E*NH) + e*NH + h] = s;
  }
}

// ---------------- gat: softmax + aggregate + residual + LN (E compile-time) ---
template<int E>
__global__ __launch_bounds__(256) void gat_kernel(
    const uint16_t* __restrict__ vg, const uint16_t* __restrict__ xc,
    const int* __restrict__ edges, const float* __restrict__ sexg,
    const int* __restrict__ elg,
    const uint16_t* __restrict__ gw, const uint16_t* __restrict__ bw,
    uint16_t* __restrict__ xc_out, uint16_t* __restrict__ y,
    int ycol, int graph)
{
  __shared__ uint16_t v2s[JC*NH*32];
  __shared__ float sexs[EMAX*NH];
  __shared__ float smax[NH];
  __shared__ int edst[EMAX];
  __shared__ uint16_t glb[2*CH];

  int f = blockIdx.x;
  int t = threadIdx.x;
  const uint16_t* vf = vg + (long)f * JC * 512;
  const int EN = E * NH;                 // compile-time

  #pragma unroll
  for (int i=0;i<3;i++){
    int g = i*256 + t;
    int r = g >> 2, cs = g & 3;
    int c = cs ^ ((r >> 1) & 3);
    int j = r >> 3, h = r & 7;
    const uint16_t* s2 = vf + j*512 + h*64 + 32 + c*8;
    __builtin_amdgcn_global_load_lds((const GLOBAL_AS void*)s2,
        (LDS_AS void*)(v2s + g*8), 16, 0, 0);
  }
  if (t < E) edst[t] = edges[E + t];
  if (t < (EN >> 2)) ((f4v*)sexs)[t] = ((const f4v*)(sexg + (long)f*EN))[t];
  glb[t] = gw[t]; glb[256 + t] = bw[t];
  __syncthreads();

  if (t < 64){
    int h = t & 7;
    float m = -3.4e38f;
    for (int e = t >> 3; e < E; e += 8) m = fmaxf(m, sexs[e*8 + h]);
    m = fmaxf(m, __shfl_xor(m, 8, 64));
    m = fmaxf(m, __shfl_xor(m, 16, 64));
    m = fmaxf(m, __shfl_xor(m, 32, 64));
    if (t < 8) smax[t] = m;
  }
  __syncthreads();

  if (t < JC*NH){
    int j = t >> 3, h = t & 7;
    int deg = elg[graph*24 + j];
    const int* lst = elg + 48 + (graph*24 + j)*8;
    float mh = smax[h];
    float ex[8];
    float sig = 1e-10f;
    int el[8];
    #pragma unroll
    for (int i=0;i<8;i++){
      float v = 0.f; int e = 0;
      if (i < deg){ e = lst[i]; v = __builtin_amdgcn_exp2f((sexs[e*8+h] - mh) * 1.44269504f); }
      el[i] = e; ex[i] = v; sig += v;
    }
    float inv = 1.f / sig;
    float acc[32];
    #pragma unroll
    for (int d=0;d<32;d++) acc[d] = 0.f;
    #pragma unroll
    for (int i=0;i<8;i++){
      if (i < deg){
        float wgt = ex[i] * inv;
        int r = edst[el[i]]*8 + h;
        int sw = (r >> 1) & 3;
        #pragma unroll
        for (int c=0;c<4;c++){
          s8v v = *(const s8v*)(v2s + r*32 + (c ^ sw)*8);
          #pragma unroll
          for (int u=0;u<8;u++) acc[c*8+u] += wgt * b2f((uint16_t)v[u]);
        }
      }
    }

    const uint16_t* v1p = vf + j*512 + h*64;
    const uint16_t* xp = xc + (long)f*JC*CH + t*32;
    float pre[32]; float sum = 0.f, sq = 0.f;
    #pragma unroll
    for (int c=0;c<4;c++){
      s8v v1 = *(const s8v*)(v1p + c*8);
      s8v xv = *(const s8v*)(xp + c*8);
      #pragma unroll
      for (int u=0;u<8;u++){
        float p = b2f((uint16_t)xv[u]) + 0.2f*b2f((uint16_t)v1[u]) + 0.8f*acc[c*8+u];
        pre[c*8+u] = p; sum += p; sq += p*p;
      }
    }
    #pragma unroll
    for (int m=1;m<8;m<<=1){ sum += __shfl_xor(sum, m, 64); sq += __shfl_xor(sq, m, 64); }
    float mean = sum * (1.f/256.f);
    float var = sq * (1.f/256.f) - mean*mean;
    float rstd = rsqrtf(var + 1e-5f);
    uint16_t* xo = xc_out + (long)f*JC*CH + t*32;
    uint16_t* yo = (j < 17) ? (y + (long)(f*17 + j)*K2 + ycol + h*32) : (uint16_t*)0;
    #pragma unroll
    for (int d0=0; d0<32; d0+=8){
      s8v ov;
      #pragma unroll
      for (int u=0;u<8;u++){
        int c = h*32 + d0 + u;
        float val = (pre[d0+u]-mean)*rstd*b2f(glb[c]) + b2f(glb[256+c]);
        ov[u] = (short)f2b(val);
      }
      *(s8v*)(xo + d0) = ov;
      if (yo) *(s8v*)(yo + d0) = ov;
    }
  }
}

// ---------------- final bias + LN --------------------------------------------
__global__ __launch_bounds__(256) void final_ln(const float* __restrict__ pre,
    const uint16_t* __restrict__ pb, const uint16_t* __restrict__ gp,
    const uint16_t* __restrict__ bp, const int* __restrict__ flag,
    void* __restrict__ out){
  int row = blockIdx.x*4 + (threadIdx.x>>6);
  int lane = threadIdx.x & 63;
  const float* p = pre + (long)row*CH + lane*4;
  f4v pv = *(const f4v*)p;
  float v[4]; float sum = 0.f, sq = 0.f;
  #pragma unroll
  for (int i=0;i<4;i++){ int c = lane*4+i; v[i] = pv[i] + b2f(pb[c]); sum += v[i]; sq += v[i]*v[i]; }
  #pragma unroll
  for (int m=1;m<64;m<<=1){ sum += __shfl_xor(sum, m, 64); sq += __shfl_xor(sq, m, 64); }
  float mean = sum * (1.f/256.f);
  float var = sq * (1.f/256.f) - mean*mean;
  float rstd = rsqrtf(var + 1e-5f);
  float o[4];
  #pragma unroll
  for (int i=0;i<4;i++){
    int c = lane*4+i;
    o[i] = (v[i]-mean)*rstd*b2f(gp[c]) + b2f(bp[c]);
  }
  if (*flag){
    s4v ov;
    #pragma unroll
    for (int i=0;i<4;i++) ov[i] = (short)f2b(o[i]);
    *(s4v*)((uint16_t*)out + (long)row*CH + lane*4) = ov;
  } else {
    f4v ov;
    #pragma unroll
    for (int i=0;i<4;i++) ov[i] = o[i];
    *(f4v*)((float*)out + (long)row*CH + lane*4) = ov;
  }
}

// ---------------- launch ------------------------------------------------------
extern "C" void kernel_launch(void* const* d_in, const int* in_sizes, int n_in,
                              void* d_out, int out_size, void* d_ws, size_t ws_size,
                              hipStream_t stream){
  const int* eskel = (const int*)d_in[21];
  const int* ecay  = (const int*)d_in[22];

  char* ws = (char*)d_ws;
  const size_t QKV_B  = (size_t)M1 * N1 * 2;
  const size_t XC_B   = (size_t)M1 * CH * 2;
  const size_t Y_B    = (size_t)M2 * K2 * 2;
  const size_t ARENA_OFF = QKV_B + 2*XC_B + Y_B;
  const size_t ARENA_B = 7543808L * 2;
  uint16_t* vout = (uint16_t*)ws;
  float*    pre  = (float*)ws;
  uint16_t* xcA = (uint16_t*)(ws + QKV_B);
  uint16_t* xcB = (uint16_t*)(ws + QKV_B + XC_B);
  uint16_t* y   = (uint16_t*)(ws + QKV_B + 2*XC_B);
  uint16_t* arena = (uint16_t*)(ws + ARENA_OFF);
  int*      flag  = (int*)(ws + ARENA_OFF + ARENA_B);
  int*      elg   = flag + 16;
  uint16_t* wv    = (uint16_t*)(ws + ARENA_OFF + ARENA_B + 4096);
  float*    sexg  = (float*)arena;

  const uint16_t* x_bf = arena;
  const uint16_t* wq[4] = {arena + 5640192, arena + 6033984, arena + 6427776, arena + 6821568};
  const uint16_t* aw[4] = {arena + 6033408, arena + 6427200, arena + 6820992, arena + 7214784};
  const uint16_t* gg[4] = {arena + 6033472, arena + 6427264, arena + 6821056, arena + 7214848};
  const uint16_t* bb[4] = {arena + 6033728, arena + 6427520, arena + 6821312, arena + 7215104};
  const uint16_t* pw = arena + 7215360;
  const uint16_t* pb = arena + 7543040;
  const uint16_t* gp = arena + 7543296;
  const uint16_t* bp = arena + 7543552;

  detect_kernel<<<1, 256, 0, stream>>>((const uint16_t*)d_in[0], flag);

  Ptrs ptrs;
  for (int i = 0; i < 21; i++) ptrs.p[i] = d_in[i];
  convert_kernel<<<3684, 256, 0, stream>>>(ptrs, flag, arena);

  prep_kernel<<<53696, 256, 0, stream>>>(x_bf, xcA, y);
  build_elist<<<1, 64, 0, stream>>>(eskel, ecay, elg);

  WPtrs wp = {{wq[0], wq[1], wq[2], wq[3]}};
  wv_copy<<<256, 256, 0, stream>>>(wp, wv);

  uint16_t* xcs[2] = {xcA, xcB};
  for (int L = 0; L < 4; ++L){
    const int* ed = (L & 1) ? ecay : eskel;
    if (L & 1) qk_logit<120><<<2592, 512, 0, stream>>>(xcs[L & 1], wq[L], aw[L], ed, sexg);
    else       qk_logit<49> <<<2592, 512, 0, stream>>>(xcs[L & 1], wq[L], aw[L], ed, sexg);
    gemm_bt<0><<<972, 256, 0, stream>>>(xcs[L & 1], wv + (long)L*512*256, vout,
                                        M1, 512, K1, 4);
    if (L & 1) gat_kernel<120><<<F_FRAMES, 256, 0, stream>>>(vout, xcs[L & 1], ed, sexg, elg,
                                             gg[L], bb[L], xcs[(L + 1) & 1], y, (L + 1) * 256, 1);
    else       gat_kernel<49> <<<F_FRAMES, 256, 0, stream>>>(vout, xcs[L & 1], ed, sexg, elg,
                                             gg[L], bb[L], xcs[(L + 1) & 1], y, (L + 1) * 256, 0);
  }
  gemm_bt<1><<<346, 256, 0, stream>>>(y, pw, pre, M2, N2, K2, 2);
  final_ln<<<5508, 256, 0, stream>>>(pre, pb, gp, bp, flag, d_out);
}

// Round 11
// 407.102 us; speedup vs baseline: 2.3130x; 1.0429x over previous
//
#include <hip/hip_runtime.h>
#include <stdint.h>

#define F_FRAMES 1296
#define JC 24
#define CH 256
#define NH 8
#define EMAX 120
#define M1 31104
#define N1 1536
#define K1 256
#define M2 22144
#define MREAL 22032
#define K2 1280
#define N2 256

typedef __attribute__((ext_vector_type(8))) short s8v;
typedef __attribute__((ext_vector_type(4))) short s4v;
typedef __attribute__((ext_vector_type(4))) float f4v;

#define GLOBAL_AS __attribute__((address_space(1)))
#define LDS_AS __attribute__((address_space(3)))

__device__ __forceinline__ float b2f(uint16_t u){
  union { float f; uint32_t u; } v; v.u = ((uint32_t)u) << 16; return v.f;
}
__device__ __forceinline__ uint16_t f2b(float f){
  union { float f; uint32_t u; } v; v.f = f;
  uint32_t u = v.u;
  uint32_t r = (u + 0x7fffu + ((u >> 16) & 1u)) >> 16;
  return (uint16_t)r;
}

// ---------------- dtype detection -------------------------------------------
__global__ __launch_bounds__(256) void detect_kernel(const uint16_t* __restrict__ x,
                                                     int* __restrict__ flag){
  __shared__ int cnt;
  if (threadIdx.x == 0) cnt = 0;
  __syncthreads();
  int good = 0;
  for (int i = threadIdx.x; i < 512; i += 256){
    uint16_t v = x[i];
    int e = (v >> 7) & 0xFF;
    good += (e >= 115 && e <= 131) ? 1 : 0;
  }
  atomicAdd(&cnt, good);
  __syncthreads();
  if (threadIdx.x == 0) *flag = (cnt >= 400) ? 1 : 0;
}

// ---------------- convert all float inputs into a bf16 arena ----------------
struct Ptrs { const void* p[21]; };

__constant__ int c_off[22] = {
  0, 5640192, 6033408, 6033472, 6033728, 6033984, 6427200, 6427264, 6427520,
  6427776, 6820992, 6821056, 6821312, 6821568, 7214784, 7214848, 7215104,
  7215360, 7543040, 7543296, 7543552, 7543808};

__global__ __launch_bounds__(256) void convert_kernel(Ptrs ptrs,
        const int* __restrict__ flag, uint16_t* __restrict__ arena){
  long base = ((long)blockIdx.x * 256 + threadIdx.x) * 8;
  if (base >= 7543808L) return;
  int seg = 0;
  while (c_off[seg + 1] <= base) seg++;
  long loc = base - c_off[seg];
  if (*flag){
    *(s8v*)(arena + base) = *(const s8v*)((const uint16_t*)ptrs.p[seg] + loc);
  } else {
    const float* s = (const float*)ptrs.p[seg] + loc;
    f4v a = *(const f4v*)s;
    f4v b = *(const f4v*)(s + 4);
    s8v o;
    #pragma unroll
    for (int u = 0; u < 4; u++){ o[u] = (short)f2b(a[u]); o[4+u] = (short)f2b(b[u]); }
    *(s8v*)(arena + base) = o;
  }
}

// ---------------- prep ---------------------------------------------------------
__global__ __launch_bounds__(256) void prep_kernel(const uint16_t* __restrict__ x,
                     uint16_t* __restrict__ xc0, uint16_t* __restrict__ y){
  long i = (long)blockIdx.x * 256 + threadIdx.x;
  const long n1 = (long)F_FRAMES * JC * CH;
  const long n2 = (long)MREAL * CH;
  const long n3 = (long)(M2 - MREAL) * K2;
  if (i < n1){
    long f = i / (JC*CH); long r = i % (JC*CH);
    int j = (int)(r >> 8); int c = (int)(r & 255);
    uint16_t v = 0;
    if (j < 17) v = x[(f*17 + j)*CH + c];
    xc0[i] = v;
  } else if (i < n1 + n2){
    long i2 = i - n1;
    long row = i2 >> 8; int c = (int)(i2 & 255);
    y[row*K2 + c] = x[i2];
  } else if (i < n1 + n2 + n3){
    long i3 = i - n1 - n2;
    long row = MREAL + i3 / K2; int c = (int)(i3 % K2);
    y[row*K2 + c] = 0;
  }
}

// ---------------- build per-src edge lists (once per call) -------------------
__global__ __launch_bounds__(64) void build_elist(const int* __restrict__ eskel,
        const int* __restrict__ ecay, int* __restrict__ out){
  int t = threadIdx.x;
  int g = t >> 5, j = t & 31;
  if (j < 24){
    const int* ed = g ? ecay : eskel;
    int E = g ? 120 : 49;
    int c = 0;
    for (int e = 0; e < E; e++)
      if (ed[e] == j){ out[48 + (g*24 + j)*8 + c] = e; c++; }
    out[g*24 + j] = c;
  }
}

// ---------------- wv_copy: gather v-rows of all 4 W's into [512][256] --------
struct WPtrs { const uint16_t* w[4]; };
__global__ __launch_bounds__(256) void wv_copy(WPtrs wp, uint16_t* __restrict__ wv){
  int g = blockIdx.x * 256 + threadIdx.x;
  int L = g >> 14;
  int loc = g & 16383;
  int row = loc >> 5;
  int col = (loc & 31) * 8;
  int wrow = (row >> 6) * 192 + 128 + (row & 63);
  *(s8v*)(wv + ((long)L*512 + row)*256 + col) =
      *(const s8v*)(wp.w[L] + (long)wrow*256 + col);
}

// ---------------- GEMM: XCD swizzle + T2 chunk-XOR LDS swizzle ----------------
template<int OUT_F32>
__global__ __launch_bounds__(256) void gemm_bt(const uint16_t* __restrict__ A,
        const uint16_t* __restrict__ B, void* __restrict__ Cv,
        int M, int N, int K, int nbn){
  __shared__ uint16_t As[128*64];
  __shared__ uint16_t Bs[128*64];
  int t = threadIdx.x;
  int lane = t & 63, w = t >> 6;
  int wr = (w >> 1) * 64, wc = (w & 1) * 64;

  int total = gridDim.x;
  int q = total >> 3, r = total & 7;
  int orig = blockIdx.x;
  int xcd = orig & 7, loc = orig >> 3;
  int wgid = (xcd < r ? xcd*(q+1) : r*(q+1) + (xcd-r)*q) + loc;
  long bm = (long)(wgid / nbn) * 128;
  long bn = (long)(wgid % nbn) * 128;

  f4v acc[4][4];
  #pragma unroll
  for (int i=0;i<4;i++){
    #pragma unroll
    for (int jq=0;jq<4;jq++) acc[i][jq] = (f4v){0.f,0.f,0.f,0.f};
  }
  const int nk = K >> 6;
  for (int kt = 0; kt < nk; ++kt){
    const uint16_t* Ag = A + bm * K + kt*64;
    const uint16_t* Bg = B + bn * K + kt*64;
    #pragma unroll
    for (int i=0;i<4;i++){
      int flat = i*256 + t;
      int row = flat >> 3, col = ((flat ^ row) & 7) << 3;
      __builtin_amdgcn_global_load_lds(
        (const GLOBAL_AS void*)(Ag + (long)row*K + col),
        (LDS_AS void*)(As + flat*8), 16, 0, 0);
    }
    #pragma unroll
    for (int i=0;i<4;i++){
      int flat = i*256 + t;
      int row = flat >> 3, col = ((flat ^ row) & 7) << 3;
      __builtin_amdgcn_global_load_lds(
        (const GLOBAL_AS void*)(Bg + (long)row*K + col),
        (LDS_AS void*)(Bs + flat*8), 16, 0, 0);
    }
    __syncthreads();
    #pragma unroll
    for (int kk=0; kk<2; ++kk){
      s8v af[4], bfr[4];
      int ch = kk*4 + (lane>>4);
      #pragma unroll
      for (int mi=0;mi<4;mi++){
        int row = wr + mi*16 + (lane&15);
        af[mi] = *(const s8v*)(As + row*64 + ((ch ^ (row&7))<<3));
      }
      #pragma unroll
      for (int ni=0;ni<4;ni++){
        int row = wc + ni*16 + (lane&15);
        bfr[ni] = *(const s8v*)(Bs + row*64 + ((ch ^ (row&7))<<3));
      }
      #pragma unroll
      for (int mi=0;mi<4;mi++){
        #pragma unroll
        for (int ni=0;ni<4;ni++)
          acc[mi][ni] = __builtin_amdgcn_mfma_f32_16x16x32_bf16(af[mi], bfr[ni], acc[mi][ni], 0,0,0);
      }
    }
    __syncthreads();
  }
  #pragma unroll
  for (int mi=0;mi<4;mi++){
    #pragma unroll
    for (int ni=0;ni<4;ni++){
      long col = bn + wc + ni*16 + (lane & 15);
      #pragma unroll
      for (int r2=0;r2<4;r2++){
        long row = bm + wr + mi*16 + (lane>>4)*4 + r2;
        if (OUT_F32) ((float*)Cv)[row*N + col] = acc[mi][ni][r2];
        else ((uint16_t*)Cv)[row*N + col] = f2b(acc[mi][ni][r2]);
      }
    }
  }
}

// ---------------- qk GEMM + fused logits, 512 threads, E compile-time ---------
// Logit phase: 8-lane group owns edge e (addrs hoisted); fl inner loop uses
// ds_read offset immediates (row swizzle is fl-invariant since 24 % 8 == 0).
template<int E>
__global__ __launch_bounds__(512) void qk_logit(
    const uint16_t* __restrict__ xc_in, const uint16_t* __restrict__ W,
    const uint16_t* __restrict__ aw, const int* __restrict__ edges,
    float* __restrict__ sexg)
{
  __shared__ uint16_t AB[14336];
  __shared__ float awf[64];
  __shared__ int esrc[EMAX], edst[EMAX];

  int t = threadIdx.x;
  int lane = t & 63, w = t >> 6;
  int wr = w >> 2, wc = w & 3;

  int orig = blockIdx.x;                 // 2592 = 8*324
  int wgid = (orig & 7) * 324 + (orig >> 3);
  int mp = wgid >> 3;
  int h  = wgid & 7;

  if (t < E){ esrc[t] = edges[t]; edst[t] = edges[E+t]; }
  if (t >= 128 && t < 192) awf[t-128] = b2f(aw[t-128]);

  uint16_t* As = AB;
  uint16_t* Bs = AB + 6144;
  const uint16_t* Ag0 = xc_in + (long)mp*96*256;
  const uint16_t* Bg0 = W + (long)h*192*256;

  f4v acc[3][2];
  #pragma unroll
  for (int i=0;i<3;i++){
    acc[i][0] = (f4v){0.f,0.f,0.f,0.f};
    acc[i][1] = (f4v){0.f,0.f,0.f,0.f};
  }

  for (int kt = 0; kt < 4; ++kt){
    {
      int g = t;
      int row = g >> 3, col = ((g ^ row) & 7) << 3;
      __builtin_amdgcn_global_load_lds(
        (const GLOBAL_AS void*)(Ag0 + (long)row*256 + kt*64 + col),
        (LDS_AS void*)(As + g*8), 16, 0, 0);
      if (t < 256){
        g = 512 + t;
        row = g >> 3; col = ((g ^ row) & 7) << 3;
        __builtin_amdgcn_global_load_lds(
          (const GLOBAL_AS void*)(Ag0 + (long)row*256 + kt*64 + col),
          (LDS_AS void*)(As + g*8), 16, 0, 0);
      }
    }
    #pragma unroll
    for (int i=0;i<2;i++){
      int g = i*512 + t;
      int row = g >> 3, col = ((g ^ row) & 7) << 3;
      __builtin_amdgcn_global_load_lds(
        (const GLOBAL_AS void*)(Bg0 + (long)row*256 + kt*64 + col),
        (LDS_AS void*)(Bs + g*8), 16, 0, 0);
    }
    __syncthreads();
    #pragma unroll
    for (int kk=0; kk<2; ++kk){
      s8v af[3], bfr[2];
      int ch = kk*4 + (lane>>4);
      #pragma unroll
      for (int mi=0;mi<3;mi++){
        int row = wr*48 + mi*16 + (lane&15);
        af[mi] = *(const s8v*)(As + row*64 + ((ch ^ (row&7))<<3));
      }
      #pragma unroll
      for (int ni=0;ni<2;ni++){
        int row = wc*32 + ni*16 + (lane&15);
        bfr[ni] = *(const s8v*)(Bs + row*64 + ((ch ^ (row&7))<<3));
      }
      #pragma unroll
      for (int mi=0;mi<3;mi++){
        #pragma unroll
        for (int ni=0;ni<2;ni++)
          acc[mi][ni] = __builtin_amdgcn_mfma_f32_16x16x32_bf16(af[mi], bfr[ni], acc[mi][ni], 0,0,0);
      }
    }
    __syncthreads();
  }

  uint16_t* qs = AB;
  #pragma unroll
  for (int mi=0;mi<3;mi++){
    #pragma unroll
    for (int ni=0;ni<2;ni++){
      int col = wc*32 + ni*16 + (lane & 15);
      int ch = col >> 3;
      #pragma unroll
      for (int r2=0;r2<4;r2++){
        int row = wr*48 + mi*16 + (lane>>4)*4 + r2;
        int pch = (ch & 8) | ((ch ^ row) & 7);
        qs[row*128 + pch*8 + (col & 7)] = f2b(acc[mi][ni][r2]);
      }
    }
  }
  __syncthreads();

  // per-thread a-weights pre-scaled by ln2 (softplus(x)*a = a*ln2*log2(1+2^(x*l2e)))
  float aln2[8];
  {
    int ln2i = t & 7;
    #pragma unroll
    for (int u=0;u<8;u++)
      aln2[u] = awf[ln2i*8 + u] * 0.69314718056f;
  }
  int ln = t & 7;
  for (int e0 = t >> 3; e0 < E; e0 += 64){
    int ns = esrc[e0], nd = edst[e0];
    const uint16_t* qp = qs + ns*128 + ((ln ^ ns) & 7)*8;
    const uint16_t* kp = qs + nd*128 + (8 | ((ln ^ nd) & 7))*8;
    #pragma unroll
    for (int fl=0; fl<4; ++fl){
      s8v qv = *(const s8v*)(qp + fl*3072);   // ds_read offset immediate
      s8v kv = *(const s8v*)(kp + fl*3072);
      float s = 0.f;
      #pragma unroll
      for (int u=0;u<8;u++){
        float xv = b2f((uint16_t)qv[u]) + b2f((uint16_t)kv[u]);
        float e2 = __builtin_amdgcn_exp2f(xv * 1.44269504f);
        float lg = __builtin_amdgcn_logf(1.f + e2);
        s = lg * aln2[u] + s;
      }
      s += __shfl_xor(s, 1, 64);
      s += __shfl_xor(s, 2, 64);
      s += __shfl_xor(s, 4, 64);
      if (ln == 0)
        sexg[((long)mp*4 + fl)*(E*NH) + e0*NH + h] = s;
    }
  }
}

// ---------------- gat: softmax + aggregate + residual + LN (E compile-time) ---
template<int E>
__global__ __launch_bounds__(256) void gat_kernel(
    const uint16_t* __restrict__ vg, const uint16_t* __restrict__ xc,
    const int* __restrict__ edges, const float* __restrict__ sexg,
    const int* __restrict__ elg,
    const uint16_t* __restrict__ gw, const uint16_t* __restrict__ bw,
    uint16_t* __restrict__ xc_out, uint16_t* __restrict__ y,
    int ycol, int graph)
{
  __shared__ uint16_t v2s[JC*NH*32];
  __shared__ float sexs[EMAX*NH];
  __shared__ float smax[NH];
  __shared__ int edst[EMAX];
  __shared__ uint16_t glb[2*CH];

  int f = blockIdx.x;
  int t = threadIdx.x;
  const uint16_t* vf = vg + (long)f * JC * 512;
  const int EN = E * NH;

  #pragma unroll
  for (int i=0;i<3;i++){
    int g = i*256 + t;
    int r = g >> 2, cs = g & 3;
    int c = cs ^ ((r >> 1) & 3);
    int j = r >> 3, h = r & 7;
    const uint16_t* s2 = vf + j*512 + h*64 + 32 + c*8;
    __builtin_amdgcn_global_load_lds((const GLOBAL_AS void*)s2,
        (LDS_AS void*)(v2s + g*8), 16, 0, 0);
  }
  if (t < E) edst[t] = edges[E + t];
  if (t < (EN >> 2)) ((f4v*)sexs)[t] = ((const f4v*)(sexg + (long)f*EN))[t];
  glb[t] = gw[t]; glb[256 + t] = bw[t];
  __syncthreads();

  if (t < 64){
    int h = t & 7;
    float m = -3.4e38f;
    for (int e = t >> 3; e < E; e += 8) m = fmaxf(m, sexs[e*8 + h]);
    m = fmaxf(m, __shfl_xor(m, 8, 64));
    m = fmaxf(m, __shfl_xor(m, 16, 64));
    m = fmaxf(m, __shfl_xor(m, 32, 64));
    if (t < 8) smax[t] = m;
  }
  __syncthreads();

  if (t < JC*NH){
    int j = t >> 3, h = t & 7;
    int deg = elg[graph*24 + j];
    const int* lst = elg + 48 + (graph*24 + j)*8;
    float mh = smax[h];
    float ex[8];
    float sig = 1e-10f;
    int el[8];
    #pragma unroll
    for (int i=0;i<8;i++){
      float v = 0.f; int e = 0;
      if (i < deg){ e = lst[i]; v = __builtin_amdgcn_exp2f((sexs[e*8+h] - mh) * 1.44269504f); }
      el[i] = e; ex[i] = v; sig += v;
    }
    float inv = 1.f / sig;
    float acc[32];
    #pragma unroll
    for (int d=0;d<32;d++) acc[d] = 0.f;
    #pragma unroll
    for (int i=0;i<8;i++){
      if (i < deg){
        float wgt = ex[i] * inv;
        int r = edst[el[i]]*8 + h;
        int sw = (r >> 1) & 3;
        #pragma unroll
        for (int c=0;c<4;c++){
          s8v v = *(const s8v*)(v2s + r*32 + (c ^ sw)*8);
          #pragma unroll
          for (int u=0;u<8;u++) acc[c*8+u] += wgt * b2f((uint16_t)v[u]);
        }
      }
    }

    const uint16_t* v1p = vf + j*512 + h*64;
    const uint16_t* xp = xc + (long)f*JC*CH + t*32;
    float pre[32]; float sum = 0.f, sq = 0.f;
    #pragma unroll
    for (int c=0;c<4;c++){
      s8v v1 = *(const s8v*)(v1p + c*8);
      s8v xv = *(const s8v*)(xp + c*8);
      #pragma unroll
      for (int u=0;u<8;u++){
        float p = b2f((uint16_t)xv[u]) + 0.2f*b2f((uint16_t)v1[u]) + 0.8f*acc[c*8+u];
        pre[c*8+u] = p; sum += p; sq += p*p;
      }
    }
    #pragma unroll
    for (int m=1;m<8;m<<=1){ sum += __shfl_xor(sum, m, 64); sq += __shfl_xor(sq, m, 64); }
    float mean = sum * (1.f/256.f);
    float var = sq * (1.f/256.f) - mean*mean;
    float rstd = rsqrtf(var + 1e-5f);
    uint16_t* xo = xc_out + (long)f*JC*CH + t*32;
    uint16_t* yo = (j < 17) ? (y + (long)(f*17 + j)*K2 + ycol + h*32) : (uint16_t*)0;
    #pragma unroll
    for (int d0=0; d0<32; d0+=8){
      s8v ov;
      #pragma unroll
      for (int u=0;u<8;u++){
        int c = h*32 + d0 + u;
        float val = (pre[d0+u]-mean)*rstd*b2f(glb[c]) + b2f(glb[256+c]);
        ov[u] = (short)f2b(val);
      }
      *(s8v*)(xo + d0) = ov;
      if (yo) *(s8v*)(yo + d0) = ov;
    }
  }
}

// ---------------- final bias + LN --------------------------------------------
__global__ __launch_bounds__(256) void final_ln(const float* __restrict__ pre,
    const uint16_t* __restrict__ pb, const uint16_t* __restrict__ gp,
    const uint16_t* __restrict__ bp, const int* __restrict__ flag,
    void* __restrict__ out){
  int row = blockIdx.x*4 + (threadIdx.x>>6);
  int lane = threadIdx.x & 63;
  const float* p = pre + (long)row*CH + lane*4;
  f4v pv = *(const f4v*)p;
  float v[4]; float sum = 0.f, sq = 0.f;
  #pragma unroll
  for (int i=0;i<4;i++){ int c = lane*4+i; v[i] = pv[i] + b2f(pb[c]); sum += v[i]; sq += v[i]*v[i]; }
  #pragma unroll
  for (int m=1;m<64;m<<=1){ sum += __shfl_xor(sum, m, 64); sq += __shfl_xor(sq, m, 64); }
  float mean = sum * (1.f/256.f);
  float var = sq * (1.f/256.f) - mean*mean;
  float rstd = rsqrtf(var + 1e-5f);
  float o[4];
  #pragma unroll
  for (int i=0;i<4;i++){
    int c = lane*4+i;
    o[i] = (v[i]-mean)*rstd*b2f(gp[c]) + b2f(bp[c]);
  }
  if (*flag){
    s4v ov;
    #pragma unroll
    for (int i=0;i<4;i++) ov[i] = (short)f2b(o[i]);
    *(s4v*)((uint16_t*)out + (long)row*CH + lane*4) = ov;
  } else {
    f4v ov;
    #pragma unroll
    for (int i=0;i<4;i++) ov[i] = o[i];
    *(f4v*)((float*)out + (long)row*CH + lane*4) = ov;
  }
}

// ---------------- launch ------------------------------------------------------
extern "C" void kernel_launch(void* const* d_in, const int* in_sizes, int n_in,
                              void* d_out, int out_size, void* d_ws, size_t ws_size,
                              hipStream_t stream){
  const int* eskel = (const int*)d_in[21];
  const int* ecay  = (const int*)d_in[22];

  char* ws = (char*)d_ws;
  const size_t QKV_B  = (size_t)M1 * N1 * 2;
  const size_t XC_B   = (size_t)M1 * CH * 2;
  const size_t Y_B    = (size_t)M2 * K2 * 2;
  const size_t ARENA_OFF = QKV_B + 2*XC_B + Y_B;
  const size_t ARENA_B = 7543808L * 2;
  uint16_t* vout = (uint16_t*)ws;
  float*    pre  = (float*)ws;
  uint16_t* xcA = (uint16_t*)(ws + QKV_B);
  uint16_t* xcB = (uint16_t*)(ws + QKV_B + XC_B);
  uint16_t* y   = (uint16_t*)(ws + QKV_B + 2*XC_B);
  uint16_t* arena = (uint16_t*)(ws + ARENA_OFF);
  int*      flag  = (int*)(ws + ARENA_OFF + ARENA_B);
  int*      elg   = flag + 16;
  uint16_t* wv    = (uint16_t*)(ws + ARENA_OFF + ARENA_B + 4096);
  float*    sexg  = (float*)arena;

  const uint16_t* x_bf = arena;
  const uint16_t* wq[4] = {arena + 5640192, arena + 6033984, arena + 6427776, arena + 6821568};
  const uint16_t* aw[4] = {arena + 6033408, arena + 6427200, arena + 6820992, arena + 7214784};
  const uint16_t* gg[4] = {arena + 6033472, arena + 6427264, arena + 6821056, arena + 7214848};
  const uint16_t* bb[4] = {arena + 6033728, arena + 6427520, arena + 6821312, arena + 7215104};
  const uint16_t* pw = arena + 7215360;
  const uint16_t* pb = arena + 7543040;
  const uint16_t* gp = arena + 7543296;
  const uint16_t* bp = arena + 7543552;

  detect_kernel<<<1, 256, 0, stream>>>((const uint16_t*)d_in[0], flag);

  Ptrs ptrs;
  for (int i = 0; i < 21; i++) ptrs.p[i] = d_in[i];
  convert_kernel<<<3684, 256, 0, stream>>>(ptrs, flag, arena);

  prep_kernel<<<53696, 256, 0, stream>>>(x_bf, xcA, y);
  build_elist<<<1, 64, 0, stream>>>(eskel, ecay, elg);

  WPtrs wp = {{wq[0], wq[1], wq[2], wq[3]}};
  wv_copy<<<256, 256, 0, stream>>>(wp, wv);

  uint16_t* xcs[2] = {xcA, xcB};
  for (int L = 0; L < 4; ++L){
    const int* ed = (L & 1) ? ecay : eskel;
    if (L & 1) qk_logit<120><<<2592, 512, 0, stream>>>(xcs[L & 1], wq[L], aw[L], ed, sexg);
    else       qk_logit<49> <<<2592, 512, 0, stream>>>(xcs[L & 1], wq[L], aw[L], ed, sexg);
    gemm_bt<0><<<972, 256, 0, stream>>>(xcs[L & 1], wv + (long)L*512*256, vout,
                                        M1, 512, K1, 4);
    if (L & 1) gat_kernel<120><<<F_FRAMES, 256, 0, stream>>>(vout, xcs[L & 1], ed, sexg, elg,
                                             gg[L], bb[L], xcs[(L + 1) & 1], y, (L + 1) * 256, 1);
    else       gat_kernel<49> <<<F_FRAMES, 256, 0, stream>>>(vout, xcs[L & 1], ed, sexg, elg,
                                             gg[L], bb[L], xcs[(L + 1) & 1], y, (L + 1) * 256, 0);
  }
  gemm_bt<1><<<346, 256, 0, stream>>>(y, pw, pre, M2, N2, K2, 2);
  final_ln<<<5508, 256, 0, stream>>>(pre, pb, gp, bp, flag, d_out);
}